// Round 6
// baseline (532.148 us; speedup 1.0000x reference)
//
#include <hip/hip_runtime.h>
#include <math.h>

#define NN 50000
#define NE 640000
#define H 128
#define EPB 64        // edges per block (512 threads, 8 waves = 4 feat-tiles x 2 edge-halves)
#define NPB 64        // nodes per block (512 threads)
#define ZB 280        // LDS stride (bf16) for z rows (560 B; 140 words = 12 mod 32)
#define BB 136        // LDS stride (bf16) for 128-wide buffers (272 B)
#define KP1 288       // padded K for layer 1 (280 -> 288; w1t zero-padded so z overread is harmless)
#define NZB 264       // LDS stride (bf16) for node 256-wide input (528 B)
#define NBPAD 50176   // 50000 rounded up to 256*196
#define HISTB (NE / 256)      // 2500
#define CONVB 464             // 118784 weight elems / 256
#define ALLOCB (NBPAD / 256)  // 196
#define HCONVB 3125           // 800000 ushort8-groups / 256

typedef __attribute__((ext_vector_type(8))) unsigned short u16x8;
typedef __attribute__((ext_vector_type(8))) __bf16 bf16x8;
typedef __attribute__((ext_vector_type(2))) __bf16 bf16x2;
typedef __attribute__((ext_vector_type(4))) float f32x4;

__device__ __forceinline__ float frcp(float x) {
#if __has_builtin(__builtin_amdgcn_rcpf)
    return __builtin_amdgcn_rcpf(x);   // raw v_rcp_f32, no Newton refine
#else
    return 1.0f / x;
#endif
}

__device__ __forceinline__ float silu_f(float v) {
    return v * frcp(1.0f + __expf(-v));
}

__device__ __forceinline__ float sigmoid_f(float v) {
    return frcp(1.0f + __expf(-v));
}

__device__ __forceinline__ float tanh_f(float v) {
    // tanh(x) = 1 - 2/(e^{2x}+1); exact at +-inf, fine for |err|~1e-6
    return 1.0f - 2.0f * frcp(1.0f + __expf(2.0f * v));
}

__device__ __forceinline__ unsigned short f2bf(float f) {
    unsigned int u = __builtin_bit_cast(unsigned int, f);
    u += 0x7FFFu + ((u >> 16) & 1u);   // RNE
    return (unsigned short)(u >> 16);
}

__device__ __forceinline__ float bf2f(unsigned short s) {
    unsigned int u = ((unsigned int)s) << 16;
    return __builtin_bit_cast(float, u);
}

__device__ __forceinline__ unsigned int pkbf(float lo, float hi) {
#if __has_builtin(__builtin_amdgcn_cvt_pk_bf16_f32)
    bf16x2 v = __builtin_amdgcn_cvt_pk_bf16_f32(lo, hi);
    unsigned int r; __builtin_memcpy(&r, &v, 4); return r;
#else
    return (unsigned int)f2bf(lo) | ((unsigned int)f2bf(hi) << 16);
#endif
}

__device__ __forceinline__ f32x4 mfma16(u16x8 a, u16x8 b, f32x4 c) {
    return __builtin_amdgcn_mfma_f32_16x16x32_bf16(
        __builtin_bit_cast(bf16x8, a), __builtin_bit_cast(bf16x8, b), c, 0, 0, 0);
}

// ---------------- init: zero out + (cnt, gtotal) ----------------------------
__global__ __launch_bounds__(256) void init_kernel(
    float4* __restrict__ out4, int n4out,
    float4* __restrict__ ws4, int n4ws)
{
    int i = blockIdx.x * 256 + threadIdx.x;
    float4 z = make_float4(0.f, 0.f, 0.f, 0.f);
    if (i < n4out) out4[i] = z;
    else if (i - n4out < n4ws) ws4[i - n4out] = z;
}

// ---------------- hist (dst degree) || weight conversion --------------------
__global__ __launch_bounds__(256) void hist_conv_kernel(
    const int* __restrict__ ei, int* __restrict__ cnt, int histBlocks,
    const float* __restrict__ We1, const float* __restrict__ We2,
    const float* __restrict__ Wx1, const float* __restrict__ Wn1,
    const float* __restrict__ Wn2,
    unsigned short* __restrict__ w1t, unsigned short* __restrict__ w2t,
    unsigned short* __restrict__ wx1t, unsigned short* __restrict__ wn1t,
    unsigned short* __restrict__ wn2t)
{
    int b = blockIdx.x, t = threadIdx.x;
    if (b < histBlocks) {
        int i = b * 256 + t;
        atomicAdd(&cnt[ei[NE + i]], 1);
        return;
    }
    int i = (b - histBlocks) * 256 + t;
    const int S1 = 128 * KP1;
    const int S2 = 128 * 128;
    const int S3 = 128 * 256;
    if (i < S1) {
        int n = i / KP1, k = i % KP1;
        w1t[i] = (k < 280) ? f2bf(We1[k * H + n]) : (unsigned short)0;
    } else if (i < S1 + S2) {
        int j = i - S1; int n = j / H, k = j % H;
        w2t[j] = f2bf(We2[k * H + n]);
    } else if (i < S1 + 2 * S2) {
        int j = i - S1 - S2; int n = j / H, k = j % H;
        wx1t[j] = f2bf(Wx1[k * H + n]);
    } else if (i < S1 + 2 * S2 + S3) {
        int j = i - S1 - 2 * S2; int n = j / 256, k = j % 256;
        wn1t[j] = f2bf(Wn1[k * H + n]);
    } else if (i < S1 + 3 * S2 + S3) {
        int j = i - S1 - 2 * S2 - S3; int n = j / H, k = j % H;
        wn2t[j] = f2bf(Wn2[k * H + n]);
    }
}

// ---------------- run-base allocation (no scan) || h -> bf16 ----------------
__global__ __launch_bounds__(256) void alloc_hconv_kernel(
    const int* __restrict__ cnt, int* __restrict__ cur, int* __restrict__ gtot,
    const float* __restrict__ h, unsigned short* __restrict__ hb,
    int allocBlocks)
{
    int b = blockIdx.x, t = threadIdx.x;
    if (b < allocBlocks) {
        int d = b * 256 + t;
        int v = cnt[d];
        int incl = v;
        #pragma unroll
        for (int o = 1; o < 64; o <<= 1) {
            int u = __shfl_up(incl, o, 64);
            if ((t & 63) >= o) incl += u;
        }
        int total = __shfl(incl, 63, 64);
        int base = 0;
        if ((t & 63) == 63) base = atomicAdd(gtot, total);
        base = __shfl(base, 63, 64);
        cur[d] = base + incl - v;
        return;
    }
    int j = (b - allocBlocks) * 256 + t;      // j < 800000, 8 floats each
    const float4* hp = (const float4*)h + (size_t)j * 2;
    float4 a = hp[0], c = hp[1];
    uint4 pk = { pkbf(a.x, a.y), pkbf(a.z, a.w), pkbf(c.x, c.y), pkbf(c.z, c.w) };
    ((uint4*)hb)[j] = pk;
}

// ---------------- scatter: sorted payload {src, dst, ea bf16x4} -------------
__global__ __launch_bounds__(256) void scatter_kernel(
    const int* __restrict__ ei, const float* __restrict__ edge_attr,
    int* __restrict__ cur, uint4* __restrict__ epay)
{
    int i = blockIdx.x * 256 + threadIdx.x;
    int s = ei[i], d = ei[NE + i];
    float4 ea = ((const float4*)edge_attr)[i];
    int p = atomicAdd(&cur[d], 1);
    uint4 pv = { (unsigned)s, (unsigned)d, pkbf(ea.x, ea.y), pkbf(ea.z, ea.w) };
    epay[p] = pv;
}

// ---------------- edge kernel -----------------------------------------------
// 512 threads, 8 waves = 4 feat-tiles(32f) x 2 edge-halves(32e), 2x2 MFMA per
// k-step. vs the 16fx64e tiling this HALVES the block's LDS b-operand reads
// (the DS pipe was ~75% busy, the bottleneck): each edge-half is read by 4
// waves, not 8. Extra a-reads hit L2 (weights), a different pipe.
// LDS ~38.4KB -> 4 blocks/CU. min-waves 6 (8 forced a 32-VGPR spill, R4).
__global__ __launch_bounds__(512, 6) void edge_kernel(
    const float* __restrict__ h, const float* __restrict__ x,
    const int* __restrict__ ei, const float* __restrict__ edge_attr,
    const unsigned short* __restrict__ w1t, const float* __restrict__ be1,
    const unsigned short* __restrict__ w2t, const float* __restrict__ be2,
    const float* __restrict__ Winf, const float* __restrict__ binf,
    const unsigned short* __restrict__ wx1t, const float* __restrict__ bx1,
    const float* __restrict__ Wx2,
    const uint4* __restrict__ epay, const unsigned short* __restrict__ hb,
    float* __restrict__ mi, float* __restrict__ dx)
{
    // zs dead after L1 K-loop: m1 aliases zs[0:EPB*BB], m2 the next EPB*BB
    // (2*EPB*BB = 17408 shorts <= EPB*ZB = 17920). +8 slack for the overread.
    __shared__ unsigned short zs[EPB * ZB + 8];
    __shared__ float relx_s[EPB][3];
    __shared__ float eij_acc[EPB];   // init binf, ds_add partials, sigmoid in place
    __shared__ float xg_acc[EPB];    // init 0,    ds_add partials, tanh in place
    __shared__ int dst_s[EPB];
    __shared__ float winf_s[H];
    __shared__ float wx2_s[H];

    unsigned short* m1 = zs;
    unsigned short* m2 = zs + EPB * BB;

    const int t = threadIdx.x;
    // XCD-chunked bijective swizzle (gridDim.x % 8 == 0 for NE/EPB = 10000).
    int bid = blockIdx.x;
    if ((gridDim.x & 7) == 0) {
        int cpx = gridDim.x >> 3;
        bid = (bid & 7) * cpx + (bid >> 3);
    }
    const int e0 = bid * EPB;
    const bool srt = (epay != nullptr);

    if (t >= 128 && t < 256) {
        winf_s[t - 128] = Winf[t - 128];
        wx2_s[t - 128] = Wx2[t - 128];
    } else if (t >= 256 && t < 320) {
        eij_acc[t - 256] = binf[0];
        xg_acc[t - 256] = 0.f;
    } else if (t == 320) {
        uint4 zf = {0u, 0u, 0u, 0u};
        *(uint4*)(zs + EPB * ZB) = zf;   // zero the overread slack
    }

    // Gather h[dst] -> z[0:128], h[src] -> z[128:256]; 8 lanes/edge, 64 edges.
    {
        int e = t >> 3, l = t & 7;
        unsigned short* zr = zs + e * ZB;
        if (srt) {
            uint4 pv = epay[e0 + e];
            const uint4* hd = (const uint4*)(hb + (size_t)pv.y * H);
            const uint4* hs = (const uint4*)(hb + (size_t)pv.x * H);
            uint4 a0 = hd[l * 2], a1 = hd[l * 2 + 1];
            *(uint4*)(zr + l * 16) = a0;
            *(uint4*)(zr + l * 16 + 8) = a1;
            uint4 c0 = hs[l * 2], c1 = hs[l * 2 + 1];
            *(uint4*)(zr + 128 + l * 16) = c0;
            *(uint4*)(zr + 128 + l * 16 + 8) = c1;
        } else {
            int s = ei[e0 + e], d = ei[NE + e0 + e];
            const float4* hd = (const float4*)(h + (size_t)d * H);
            const float4* hs = (const float4*)(h + (size_t)s * H);
            float4 v0 = hd[l * 4 + 0], v1 = hd[l * 4 + 1];
            float4 v2 = hd[l * 4 + 2], v3 = hd[l * 4 + 3];
            uint4 p0 = { pkbf(v0.x, v0.y), pkbf(v0.z, v0.w), pkbf(v1.x, v1.y), pkbf(v1.z, v1.w) };
            uint4 p1 = { pkbf(v2.x, v2.y), pkbf(v2.z, v2.w), pkbf(v3.x, v3.y), pkbf(v3.z, v3.w) };
            *(uint4*)(zr + l * 16) = p0;
            *(uint4*)(zr + l * 16 + 8) = p1;
            float4 w0 = hs[l * 4 + 0], w1 = hs[l * 4 + 1];
            float4 w2 = hs[l * 4 + 2], w3 = hs[l * 4 + 3];
            uint4 q0 = { pkbf(w0.x, w0.y), pkbf(w0.z, w0.w), pkbf(w1.x, w1.y), pkbf(w1.z, w1.w) };
            uint4 q1 = { pkbf(w2.x, w2.y), pkbf(w2.z, w2.w), pkbf(w3.x, w3.y), pkbf(w3.z, w3.w) };
            *(uint4*)(zr + 128 + l * 16) = q0;
            *(uint4*)(zr + 128 + l * 16 + 8) = q1;
        }
    }
    // Geometry + gaussians + edge_attr; 1 thread/edge.
    if (t < EPB) {
        unsigned short* zr = zs + t * ZB;
        int s, d;
        if (srt) {
            uint4 pv = epay[e0 + t];
            s = (int)pv.x; d = (int)pv.y;
            *(unsigned int*)(zr + 276) = pv.z;   // ea[0..1] bf16
            *(unsigned int*)(zr + 278) = pv.w;   // ea[2..3] bf16
        } else {
            s = ei[e0 + t]; d = ei[NE + e0 + t];
            #pragma unroll
            for (int j = 0; j < 4; j++)
                zr[276 + j] = f2bf(edge_attr[(size_t)(e0 + t) * 4 + j]);
        }
        dst_s[t] = d;
        float rx = x[d * 3 + 0] - x[s * 3 + 0];
        float ry = x[d * 3 + 1] - x[s * 3 + 1];
        float rz = x[d * 3 + 2] - x[s * 3 + 2];
        float d2 = rx * rx + ry * ry + rz * rz;
        float dd = sqrtf(d2 + 1e-8f);
        float inv = frcp(dd + 1.0f);
        relx_s[t][0] = rx * inv;
        relx_s[t][1] = ry * inv;
        relx_s[t][2] = rz * inv;
        const float step = 10.0f / 19.0f;
        const float coeff = -0.5f / (step * step);
        #pragma unroll
        for (int g = 0; g < 20; g++) {
            float df = dd - step * (float)g;
            zr[256 + g] = f2bf(__expf(coeff * df * df));
        }
    }
    __syncthreads();                                               // B

    const int wv = t >> 6, lane = t & 63;
    const int quad = lane >> 4, r16 = lane & 15;
    const int F = (wv >> 1) * 32;        // feature tile (4 tiles of 32)
    const int EB = (wv & 1) * 32;        // edge half (2 halves of 32)

    // Layer 1: (z @ We1)^T -> silu -> m1. 32 feat x 32 edges per wave, 2x2.
    {
        f32x4 acc[2][2] = {};            // [rt][ci]
        #pragma unroll
        for (int ks = 0; ks < KP1 / 32; ks++) {
            int ko = ks * 32 + quad * 8;
            u16x8 a0 = *(const u16x8*)(w1t + (size_t)(F + r16) * KP1 + ko);
            u16x8 a1 = *(const u16x8*)(w1t + (size_t)(F + 16 + r16) * KP1 + ko);
            u16x8 b0 = *(const u16x8*)(zs + (EB + r16) * ZB + ko);
            u16x8 b1 = *(const u16x8*)(zs + (EB + 16 + r16) * ZB + ko);
            acc[0][0] = mfma16(a0, b0, acc[0][0]);
            acc[0][1] = mfma16(a0, b1, acc[0][1]);
            acc[1][0] = mfma16(a1, b0, acc[1][0]);
            acc[1][1] = mfma16(a1, b1, acc[1][1]);
        }
        __syncthreads();                                           // C
        #pragma unroll
        for (int rt = 0; rt < 2; rt++) {
            int f0 = F + rt * 16 + quad * 4;
            float4 bv = *(const float4*)(be1 + f0);
            #pragma unroll
            for (int ci = 0; ci < 2; ci++) {
                int e = EB + ci * 16 + r16;
                float s0 = silu_f(acc[rt][ci][0] + bv.x);
                float s1 = silu_f(acc[rt][ci][1] + bv.y);
                float s2 = silu_f(acc[rt][ci][2] + bv.z);
                float s3 = silu_f(acc[rt][ci][3] + bv.w);
                uint2 p = { pkbf(s0, s1), pkbf(s2, s3) };
                *(uint2*)(m1 + e * BB + f0) = p;
            }
        }
    }
    __syncthreads();                                               // D

    // Layer 2: mij -> m2 (bf16). eij dot fused; partials via ds_add_f32.
    {
        f32x4 acc[2][2] = {};
        #pragma unroll
        for (int ks = 0; ks < H / 32; ks++) {
            int ko = ks * 32 + quad * 8;
            u16x8 a0 = *(const u16x8*)(w2t + (size_t)(F + r16) * H + ko);
            u16x8 a1 = *(const u16x8*)(w2t + (size_t)(F + 16 + r16) * H + ko);
            u16x8 b0 = *(const u16x8*)(m1 + (EB + r16) * BB + ko);
            u16x8 b1 = *(const u16x8*)(m1 + (EB + 16 + r16) * BB + ko);
            acc[0][0] = mfma16(a0, b0, acc[0][0]);
            acc[0][1] = mfma16(a0, b1, acc[0][1]);
            acc[1][0] = mfma16(a1, b0, acc[1][0]);
            acc[1][1] = mfma16(a1, b1, acc[1][1]);
        }
        float ep[2] = {0.f, 0.f};
        #pragma unroll
        for (int rt = 0; rt < 2; rt++) {
            int f0 = F + rt * 16 + quad * 4;
            float4 bv = *(const float4*)(be2 + f0);
            float4 wf = *(const float4*)(winf_s + f0);
            #pragma unroll
            for (int ci = 0; ci < 2; ci++) {
                int e = EB + ci * 16 + r16;
                float s0 = silu_f(acc[rt][ci][0] + bv.x);
                float s1 = silu_f(acc[rt][ci][1] + bv.y);
                float s2 = silu_f(acc[rt][ci][2] + bv.z);
                float s3 = silu_f(acc[rt][ci][3] + bv.w);
                ep[ci] += s0 * wf.x + s1 * wf.y + s2 * wf.z + s3 * wf.w;
                uint2 p = { pkbf(s0, s1), pkbf(s2, s3) };
                *(uint2*)(m2 + e * BB + f0) = p;
            }
        }
        #pragma unroll
        for (int ci = 0; ci < 2; ci++) {
            ep[ci] += __shfl_xor(ep[ci], 16, 64);
            ep[ci] += __shfl_xor(ep[ci], 32, 64);
        }
        if (quad == 0) {
            #pragma unroll
            for (int ci = 0; ci < 2; ci++)
                atomicAdd(&eij_acc[EB + ci * 16 + r16], ep[ci]);
        }
    }
    __syncthreads();                                               // E

    // eij = sigmoid(acc); 64 threads, in place.
    if (t < EPB) eij_acc[t] = sigmoid_f(eij_acc[t]);

    // Coord layer: silu(mij @ Wx1) . Wx2, never materialized.
    {
        f32x4 acc[2][2] = {};
        #pragma unroll
        for (int ks = 0; ks < H / 32; ks++) {
            int ko = ks * 32 + quad * 8;
            u16x8 a0 = *(const u16x8*)(wx1t + (size_t)(F + r16) * H + ko);
            u16x8 a1 = *(const u16x8*)(wx1t + (size_t)(F + 16 + r16) * H + ko);
            u16x8 b0 = *(const u16x8*)(m2 + (EB + r16) * BB + ko);
            u16x8 b1 = *(const u16x8*)(m2 + (EB + 16 + r16) * BB + ko);
            acc[0][0] = mfma16(a0, b0, acc[0][0]);
            acc[0][1] = mfma16(a0, b1, acc[0][1]);
            acc[1][0] = mfma16(a1, b0, acc[1][0]);
            acc[1][1] = mfma16(a1, b1, acc[1][1]);
        }
        float xp[2] = {0.f, 0.f};
        #pragma unroll
        for (int rt = 0; rt < 2; rt++) {
            int f0 = F + rt * 16 + quad * 4;
            float4 bv = *(const float4*)(bx1 + f0);
            float4 wf = *(const float4*)(wx2_s + f0);
            #pragma unroll
            for (int ci = 0; ci < 2; ci++) {
                xp[ci] += silu_f(acc[rt][ci][0] + bv.x) * wf.x
                        + silu_f(acc[rt][ci][1] + bv.y) * wf.y
                        + silu_f(acc[rt][ci][2] + bv.z) * wf.z
                        + silu_f(acc[rt][ci][3] + bv.w) * wf.w;
            }
        }
        #pragma unroll
        for (int ci = 0; ci < 2; ci++) {
            xp[ci] += __shfl_xor(xp[ci], 16, 64);
            xp[ci] += __shfl_xor(xp[ci], 32, 64);
        }
        if (quad == 0) {
            #pragma unroll
            for (int ci = 0; ci < 2; ci++)
                atomicAdd(&xg_acc[EB + ci * 16 + r16], xp[ci]);
        }
    }
    __syncthreads();                                               // F

    // xg = tanh(acc); 64 threads, in place.
    if (t < EPB) xg_acc[t] = tanh_f(xg_acc[t]);
    __syncthreads();                                               // G

    // Segment sums over sorted runs: chunk-8 register prefetch breaks the
    // LDS-latency chain; one atomic per run; block-interior runs (dst wholly
    // owned, only in sorted mode) use a plain store.
    if (t < 128) {
        const int k = t;
        float acc = 0.f;
        int rs = 0;
        #pragma unroll
        for (int c = 0; c < EPB; c += 8) {
            float v[8];
            #pragma unroll
            for (int j = 0; j < 8; j++)
                v[j] = bf2f(m2[(c + j) * BB + k]) * eij_acc[c + j];
            #pragma unroll
            for (int j = 0; j < 8; j++) {
                int e = c + j;
                acc += v[j];
                if (e == EPB - 1 || dst_s[e + 1] != dst_s[e]) {
                    float* p = &mi[(size_t)dst_s[e] * H + k];
                    if (srt && rs > 0 && e < EPB - 1) *p = acc;
                    else atomicAdd(p, acc);
                    acc = 0.f;
                    rs = e + 1;
                }
            }
        }
    } else if (t < 131) {
        const int dd = t - 128;
        float acc = 0.f;
        int rs = 0;
        #pragma unroll
        for (int c = 0; c < EPB; c += 8) {
            float v[8];
            #pragma unroll
            for (int j = 0; j < 8; j++)
                v[j] = relx_s[c + j][dd] * xg_acc[c + j];
            #pragma unroll
            for (int j = 0; j < 8; j++) {
                int e = c + j;
                acc += v[j];
                if (e == EPB - 1 || dst_s[e + 1] != dst_s[e]) {
                    float* p = &dx[(size_t)dst_s[e] * 3 + dd];
                    if (srt && rs > 0 && e < EPB - 1) *p = acc;
                    else atomicAdd(p, acc);
                    acc = 0.f;
                    rs = e + 1;
                }
            }
        }
    }
}

// ---------------- node kernel (bf16 MFMA, 512 thr, 64 nodes) ----------------
// Same 4 feat-tile x 2 node-half wave grid as the edge kernel: halves the
// LDS b-read traffic. LDS ~33.8KB -> 4 blocks/CU.
__global__ __launch_bounds__(512, 6) void node_kernel(
    const float* __restrict__ h, const float* __restrict__ x,
    const float* __restrict__ mask,
    const unsigned short* __restrict__ wn1t, const float* __restrict__ bn1,
    const unsigned short* __restrict__ wn2t, const float* __restrict__ bn2,
    const unsigned short* __restrict__ hb,
    float* __restrict__ mi_hout, float* __restrict__ dx_xout)
{
    __shared__ unsigned short nzs[NPB * NZB];   // 16896 shorts; nbuf needs 8704

    unsigned short* nbuf = nzs;

    const int t = threadIdx.x;
    const int n0 = blockIdx.x * NPB;

    {
        int r = t >> 3, l = t & 7;
        int n = n0 + r;
        unsigned short* zr = nzs + r * NZB;
        if (n < NN) {
            const float4* mi4 = (const float4*)(mi_hout + (size_t)n * H);
            float4 v0 = mi4[l * 4 + 0], v1 = mi4[l * 4 + 1];
            float4 v2 = mi4[l * 4 + 2], v3 = mi4[l * 4 + 3];
            uint4 p0 = { pkbf(v0.x, v0.y), pkbf(v0.z, v0.w), pkbf(v1.x, v1.y), pkbf(v1.z, v1.w) };
            uint4 p1 = { pkbf(v2.x, v2.y), pkbf(v2.z, v2.w), pkbf(v3.x, v3.y), pkbf(v3.z, v3.w) };
            *(uint4*)(zr + l * 16) = p0;
            *(uint4*)(zr + l * 16 + 8) = p1;
            if (hb) {
                const uint4* hs = (const uint4*)(hb + (size_t)n * H);
                *(uint4*)(zr + 128 + l * 16) = hs[l * 2];
                *(uint4*)(zr + 128 + l * 16 + 8) = hs[l * 2 + 1];
            } else {
                const float4* h4 = (const float4*)(h + (size_t)n * H);
                float4 w0 = h4[l * 4 + 0], w1 = h4[l * 4 + 1];
                float4 w2 = h4[l * 4 + 2], w3 = h4[l * 4 + 3];
                uint4 q0 = { pkbf(w0.x, w0.y), pkbf(w0.z, w0.w), pkbf(w1.x, w1.y), pkbf(w1.z, w1.w) };
                uint4 q1 = { pkbf(w2.x, w2.y), pkbf(w2.z, w2.w), pkbf(w3.x, w3.y), pkbf(w3.z, w3.w) };
                *(uint4*)(zr + 128 + l * 16) = q0;
                *(uint4*)(zr + 128 + l * 16 + 8) = q1;
            }
        } else {
            uint4 zf = {0u, 0u, 0u, 0u};
            *(uint4*)(zr + l * 16) = zf;
            *(uint4*)(zr + l * 16 + 8) = zf;
            *(uint4*)(zr + 128 + l * 16) = zf;
            *(uint4*)(zr + 128 + l * 16 + 8) = zf;
        }
    }

    float xo = 0.f;
    int xn = -1, xdim = 0;
    if (t < NPB * 3) {
        int r = t / 3; xdim = t % 3;
        int n = n0 + r;
        if (n < NN) {
            xn = n;
            xo = x[(size_t)n * 3 + xdim] + dx_xout[(size_t)n * 3 + xdim] * mask[n];
        }
    }
    __syncthreads();

    if (xn >= 0) dx_xout[(size_t)xn * 3 + xdim] = xo;

    const int wv = t >> 6, lane = t & 63;
    const int quad = lane >> 4, r16 = lane & 15;
    const int F = (wv >> 1) * 32;        // feature tile
    const int NB = (wv & 1) * 32;        // node half

    // n1: silu(nz @ Wn1) -> nbuf (aliases nzs). 32 feat x 32 nodes per wave.
    {
        f32x4 acc[2][2] = {};
        #pragma unroll
        for (int ks = 0; ks < 2 * H / 32; ks++) {
            int ko = ks * 32 + quad * 8;
            u16x8 a0 = *(const u16x8*)(wn1t + (size_t)(F + r16) * (2 * H) + ko);
            u16x8 a1 = *(const u16x8*)(wn1t + (size_t)(F + 16 + r16) * (2 * H) + ko);
            u16x8 b0 = *(const u16x8*)(nzs + (NB + r16) * NZB + ko);
            u16x8 b1 = *(const u16x8*)(nzs + (NB + 16 + r16) * NZB + ko);
            acc[0][0] = mfma16(a0, b0, acc[0][0]);
            acc[0][1] = mfma16(a0, b1, acc[0][1]);
            acc[1][0] = mfma16(a1, b0, acc[1][0]);
            acc[1][1] = mfma16(a1, b1, acc[1][1]);
        }
        __syncthreads();
        #pragma unroll
        for (int rt = 0; rt < 2; rt++) {
            int f0 = F + rt * 16 + quad * 4;
            float4 bv = *(const float4*)(bn1 + f0);
            #pragma unroll
            for (int ci = 0; ci < 2; ci++) {
                int e = NB + ci * 16 + r16;
                float s0 = silu_f(acc[rt][ci][0] + bv.x);
                float s1 = silu_f(acc[rt][ci][1] + bv.y);
                float s2 = silu_f(acc[rt][ci][2] + bv.z);
                float s3 = silu_f(acc[rt][ci][3] + bv.w);
                uint2 p = { pkbf(s0, s1), pkbf(s2, s3) };
                *(uint2*)(nbuf + e * BB + f0) = p;
            }
        }
    }
    __syncthreads();

    // n2: (nbuf @ Wn2) + bn2 + h -> h_out
    {
        f32x4 acc[2][2] = {};
        #pragma unroll
        for (int ks = 0; ks < H / 32; ks++) {
            int ko = ks * 32 + quad * 8;
            u16x8 a0 = *(const u16x8*)(wn2t + (size_t)(F + r16) * H + ko);
            u16x8 a1 = *(const u16x8*)(wn2t + (size_t)(F + 16 + r16) * H + ko);
            u16x8 b0 = *(const u16x8*)(nbuf + (NB + r16) * BB + ko);
            u16x8 b1 = *(const u16x8*)(nbuf + (NB + 16 + r16) * BB + ko);
            acc[0][0] = mfma16(a0, b0, acc[0][0]);
            acc[0][1] = mfma16(a0, b1, acc[0][1]);
            acc[1][0] = mfma16(a1, b0, acc[1][0]);
            acc[1][1] = mfma16(a1, b1, acc[1][1]);
        }
        #pragma unroll
        for (int rt = 0; rt < 2; rt++) {
            int f0 = F + rt * 16 + quad * 4;
            float4 bv = *(const float4*)(bn2 + f0);
            #pragma unroll
            for (int ci = 0; ci < 2; ci++) {
                int n = n0 + NB + ci * 16 + r16;
                if (n < NN) {
                    float4 hv = *(const float4*)(h + (size_t)n * H + f0);
                    float4 o;
                    o.x = hv.x + acc[rt][ci][0] + bv.x;
                    o.y = hv.y + acc[rt][ci][1] + bv.y;
                    o.z = hv.z + acc[rt][ci][2] + bv.z;
                    o.w = hv.w + acc[rt][ci][3] + bv.w;
                    *(float4*)(mi_hout + (size_t)n * H + f0) = o;
                }
            }
        }
    }
}

extern "C" void kernel_launch(void* const* d_in, const int* in_sizes, int n_in,
                              void* d_out, int out_size, void* d_ws, size_t ws_size,
                              hipStream_t stream) {
    const float* h     = (const float*)d_in[0];
    const float* x     = (const float*)d_in[1];
    const int*   ei    = (const int*)d_in[2];
    const float* mask  = (const float*)d_in[3];
    const float* eattr = (const float*)d_in[4];
    const float* We1   = (const float*)d_in[5];
    const float* be1   = (const float*)d_in[6];
    const float* We2   = (const float*)d_in[7];
    const float* be2   = (const float*)d_in[8];
    const float* Winf  = (const float*)d_in[9];
    const float* binf  = (const float*)d_in[10];
    const float* Wx1   = (const float*)d_in[11];
    const float* bx1   = (const float*)d_in[12];
    const float* Wx2   = (const float*)d_in[13];
    const float* Wn1   = (const float*)d_in[14];
    const float* bn1   = (const float*)d_in[15];
    const float* Wn2   = (const float*)d_in[16];
    const float* bn2   = (const float*)d_in[17];

    float* mi = (float*)d_out;
    float* dx = mi + (size_t)NN * H;

    // ws layout (bytes):
    //   [0, 256K)            bf16 weights (237568 used)
    //   [256K, +200704)      cnt   (NBPAD ints)
    //   [.., +16)            gtotal
    //   [.., +200704)        cur   (NBPAD ints)
    //   [.., +12.8M)         hb    (bf16 h)
    //   [.., +10.24M)        epay  (uint4 per edge, dst-sorted)
    char* wsb  = (char*)d_ws;
    unsigned short* w1t  = (unsigned short*)wsb;
    unsigned short* w2t  = w1t + 128 * KP1;
    unsigned short* wx1t = w2t + 128 * H;
    unsigned short* wn1t = wx1t + 128 * H;
    unsigned short* wn2t = wn1t + 128 * 256;

    const size_t OFF_CNT  = 262144;
    const size_t OFF_GTOT = OFF_CNT + (size_t)NBPAD * 4;     // 462848
    const size_t OFF_CUR  = OFF_GTOT + 16;                   // 462864
    const size_t OFF_HB   = OFF_CUR + (size_t)NBPAD * 4;     // 663568
    const size_t OFF_EPAY = OFF_HB + (size_t)NN * H * 2;     // 13463568
    const size_t WS_NEED  = OFF_EPAY + (size_t)NE * 16;      // 23703568

    int*   cnt  = (int*)(wsb + OFF_CNT);
    int*   gtot = (int*)(wsb + OFF_GTOT);
    int*   cur  = (int*)(wsb + OFF_CUR);
    unsigned short* hb = (unsigned short*)(wsb + OFF_HB);
    uint4* epay = (uint4*)(wsb + OFF_EPAY);

    const bool full = (ws_size >= WS_NEED);

    // init: zero d_out (+ cnt/gtotal in full mode; cur is fully overwritten)
    const int n4out = (NN * H + NN * 3) / 4;
    const int n4ws  = full ? (int)((OFF_CUR - OFF_CNT) / 16) : 0;   // 12545
    init_kernel<<<(n4out + n4ws + 255) / 256, 256, 0, stream>>>(
        (float4*)d_out, n4out, (float4*)(wsb + OFF_CNT), n4ws);

    // hist || weight convert
    {
        int hb_ = full ? HISTB : 0;
        hist_conv_kernel<<<hb_ + CONVB, 256, 0, stream>>>(
            ei, cnt, hb_, We1, We2, Wx1, Wn1, Wn2, w1t, w2t, wx1t, wn1t, wn2t);
    }

    if (full) {
        // run-base alloc || h -> bf16
        alloc_hconv_kernel<<<ALLOCB + HCONVB, 256, 0, stream>>>(
            cnt, cur, gtot, h, hb, ALLOCB);
        // sorted payload scatter
        scatter_kernel<<<NE / 256, 256, 0, stream>>>(ei, eattr, cur, epay);
    }

    edge_kernel<<<NE / EPB, 512, 0, stream>>>(
        h, x, ei, eattr, w1t, be1, w2t, be2, Winf, binf, wx1t, bx1, Wx2,
        full ? epay : (const uint4*)nullptr,
        full ? hb : (const unsigned short*)nullptr,
        mi, dx);

    node_kernel<<<(NN + NPB - 1) / NPB, 512, 0, stream>>>(
        h, x, mask, wn1t, bn1, wn2t, bn2,
        full ? hb : (const unsigned short*)nullptr,
        mi, dx);
}

// Round 7
// 443.814 us; speedup vs baseline: 1.1990x; 1.1990x over previous
//
#include <hip/hip_runtime.h>
#include <math.h>

#define NN 50000
#define NE 640000
#define H 128
#define EPB 64        // edges per block (512 threads, 8 waves x 16feat x 64edges)
#define NPB 64        // nodes per block (512 threads)
#define ZB 280        // LDS stride (bf16) for z rows (560 B)
#define BB 136        // LDS stride (bf16) for 128-wide buffers (272 B)
#define KP1 288       // padded K for layer 1 (280 -> 288; w1t zero-padded, z overread harmless)
#define NZB 264       // LDS stride (bf16) for node 256-wide input (528 B)
#define NBPAD 50176   // 50000 rounded up to 256*196
#define HISTB (NE / 256)      // 2500
#define CONVB 464             // 118784 weight elems / 256
#define ALLOCB (NBPAD / 256)  // 196
#define HCONVB 3125           // 800000 ushort8-groups / 256
#define N4OUT ((NN * H + NN * 3) / 4)          // 1637500 float4 of d_out
#define ZOB ((N4OUT + 255) / 256)              // 6397 zero blocks

typedef __attribute__((ext_vector_type(8))) unsigned short u16x8;
typedef __attribute__((ext_vector_type(8))) __bf16 bf16x8;
typedef __attribute__((ext_vector_type(2))) __bf16 bf16x2;
typedef __attribute__((ext_vector_type(4))) float f32x4;

__device__ __forceinline__ float frcp(float x) {
#if __has_builtin(__builtin_amdgcn_rcpf)
    return __builtin_amdgcn_rcpf(x);   // raw v_rcp_f32, no Newton refine
#else
    return 1.0f / x;
#endif
}

__device__ __forceinline__ float silu_f(float v) {
    return v * frcp(1.0f + __expf(-v));
}

__device__ __forceinline__ float sigmoid_f(float v) {
    return frcp(1.0f + __expf(-v));
}

__device__ __forceinline__ float tanh_f(float v) {
    // tanh(x) = 1 - 2/(e^{2x}+1); exact at +-inf, fine for |err|~1e-6
    return 1.0f - 2.0f * frcp(1.0f + __expf(2.0f * v));
}

__device__ __forceinline__ unsigned short f2bf(float f) {
    unsigned int u = __builtin_bit_cast(unsigned int, f);
    u += 0x7FFFu + ((u >> 16) & 1u);   // RNE
    return (unsigned short)(u >> 16);
}

__device__ __forceinline__ float bf2f(unsigned short s) {
    unsigned int u = ((unsigned int)s) << 16;
    return __builtin_bit_cast(float, u);
}

__device__ __forceinline__ unsigned int pkbf(float lo, float hi) {
#if __has_builtin(__builtin_amdgcn_cvt_pk_bf16_f32)
    bf16x2 v = __builtin_amdgcn_cvt_pk_bf16_f32(lo, hi);
    unsigned int r; __builtin_memcpy(&r, &v, 4); return r;
#else
    return (unsigned int)f2bf(lo) | ((unsigned int)f2bf(hi) << 16);
#endif
}

__device__ __forceinline__ f32x4 mfma16(u16x8 a, u16x8 b, f32x4 c) {
    return __builtin_amdgcn_mfma_f32_16x16x32_bf16(
        __builtin_bit_cast(bf16x8, a), __builtin_bit_cast(bf16x8, b), c, 0, 0, 0);
}

// ---------------- K1: zero cnt + gtotal (tiny; must precede hist) -----------
__global__ __launch_bounds__(256) void init_small_kernel(
    float4* __restrict__ p, int n4)
{
    int i = blockIdx.x * 256 + threadIdx.x;
    if (i < n4) p[i] = make_float4(0.f, 0.f, 0.f, 0.f);
}

// ---------------- K2: hist || weight conv || zero d_out ---------------------
__global__ __launch_bounds__(256) void hist_conv_zero_kernel(
    const int* __restrict__ ei, int* __restrict__ cnt, int histBlocks,
    const float* __restrict__ We1, const float* __restrict__ We2,
    const float* __restrict__ Wx1, const float* __restrict__ Wn1,
    const float* __restrict__ Wn2,
    unsigned short* __restrict__ w1t, unsigned short* __restrict__ w2t,
    unsigned short* __restrict__ wx1t, unsigned short* __restrict__ wn1t,
    unsigned short* __restrict__ wn2t,
    float4* __restrict__ out4)
{
    int b = blockIdx.x, t = threadIdx.x;
    if (b < histBlocks) {
        atomicAdd(&cnt[ei[NE + b * 256 + t]], 1);
        return;
    }
    b -= histBlocks;
    if (b < CONVB) {
        int i = b * 256 + t;
        const int S1 = 128 * KP1;
        const int S2 = 128 * 128;
        const int S3 = 128 * 256;
        if (i < S1) {
            int n = i / KP1, k = i % KP1;
            w1t[i] = (k < 280) ? f2bf(We1[k * H + n]) : (unsigned short)0;
        } else if (i < S1 + S2) {
            int j = i - S1; int n = j / H, k = j % H;
            w2t[j] = f2bf(We2[k * H + n]);
        } else if (i < S1 + 2 * S2) {
            int j = i - S1 - S2; int n = j / H, k = j % H;
            wx1t[j] = f2bf(Wx1[k * H + n]);
        } else if (i < S1 + 2 * S2 + S3) {
            int j = i - S1 - 2 * S2; int n = j / 256, k = j % 256;
            wn1t[j] = f2bf(Wn1[k * H + n]);
        } else if (i < S1 + 3 * S2 + S3) {
            int j = i - S1 - 2 * S2 - S3; int n = j / H, k = j % H;
            wn2t[j] = f2bf(Wn2[k * H + n]);
        }
        return;
    }
    b -= CONVB;
    int i = b * 256 + t;
    if (i < N4OUT) out4[i] = make_float4(0.f, 0.f, 0.f, 0.f);
}

// ---------------- K3: run-base allocation (no scan) -------------------------
// Group order is irrelevant for the segment sum; each dst just needs a
// contiguous slice. Wave-scan cnt, one global atomicAdd per wave.
__global__ __launch_bounds__(256) void alloc_kernel(
    const int* __restrict__ cnt, int* __restrict__ cur, int* __restrict__ gtot)
{
    int t = threadIdx.x;
    int d = blockIdx.x * 256 + t;
    int v = cnt[d];
    int incl = v;
    #pragma unroll
    for (int o = 1; o < 64; o <<= 1) {
        int u = __shfl_up(incl, o, 64);
        if ((t & 63) >= o) incl += u;
    }
    int total = __shfl(incl, 63, 64);
    int base = 0;
    if ((t & 63) == 63) base = atomicAdd(gtot, total);
    base = __shfl(base, 63, 64);
    cur[d] = base + incl - v;
}

// ---------------- K4: scatter sorted payload || h -> bf16 -------------------
__global__ __launch_bounds__(256) void scatter_hconv_kernel(
    const int* __restrict__ ei, const float* __restrict__ edge_attr,
    int* __restrict__ cur, uint4* __restrict__ epay,
    const float* __restrict__ h, unsigned short* __restrict__ hb)
{
    int b = blockIdx.x, t = threadIdx.x;
    if (b < NE / 256) {
        int i = b * 256 + t;
        int s = ei[i], d = ei[NE + i];
        float4 ea = ((const float4*)edge_attr)[i];
        int p = atomicAdd(&cur[d], 1);
        uint4 pv = { (unsigned)s, (unsigned)d, pkbf(ea.x, ea.y), pkbf(ea.z, ea.w) };
        epay[p] = pv;
        return;
    }
    int j = (b - NE / 256) * 256 + t;      // j < 800000, 8 floats each
    const float4* hp = (const float4*)h + (size_t)j * 2;
    float4 a = hp[0], c = hp[1];
    uint4 pk = { pkbf(a.x, a.y), pkbf(a.z, a.w), pkbf(c.x, c.y), pkbf(c.z, c.w) };
    ((uint4*)hb)[j] = pk;
}

// ---------------- edge kernel (R5 structure, proven) ------------------------
// 512 threads, 8 waves x 16feat x 64edges: each weight line touched by ONE
// wave per block (R6's 2x2 tiling doubled weight line-touches -> -33%).
// LDS ~38.4KB -> 4 blocks/CU = hardware wave cap. min-waves 6 ((512,8)
// forced a 32-VGPR spill, R4). XCD-chunked swizzle keeps dst-sorted
// neighbor blocks on one XCD L2.
__global__ __launch_bounds__(512, 6) void edge_kernel(
    const float* __restrict__ h, const float* __restrict__ x,
    const int* __restrict__ ei, const float* __restrict__ edge_attr,
    const unsigned short* __restrict__ w1t, const float* __restrict__ be1,
    const unsigned short* __restrict__ w2t, const float* __restrict__ be2,
    const float* __restrict__ Winf, const float* __restrict__ binf,
    const unsigned short* __restrict__ wx1t, const float* __restrict__ bx1,
    const float* __restrict__ Wx2,
    const uint4* __restrict__ epay, const unsigned short* __restrict__ hb,
    float* __restrict__ mi, float* __restrict__ dx)
{
    // zs dead after L1 K-loop: m1 aliases zs[0:EPB*BB], m2 the next EPB*BB
    // (2*EPB*BB = 17408 shorts <= EPB*ZB = 17920). +8 slack for the overread.
    __shared__ unsigned short zs[EPB * ZB + 8];
    __shared__ float relx_s[EPB][3];
    __shared__ float eij_acc[EPB];   // init binf, ds_add partials, sigmoid in place
    __shared__ float xg_acc[EPB];    // init 0,    ds_add partials; tanh in consumer
    __shared__ int dst_s[EPB];
    __shared__ float winf_s[H];
    __shared__ float wx2_s[H];

    unsigned short* m1 = zs;
    unsigned short* m2 = zs + EPB * BB;

    const int t = threadIdx.x;
    // XCD-chunked bijective swizzle (gridDim.x % 8 == 0 for NE/EPB = 10000).
    int bid = blockIdx.x;
    if ((gridDim.x & 7) == 0) {
        int cpx = gridDim.x >> 3;
        bid = (bid & 7) * cpx + (bid >> 3);
    }
    const int e0 = bid * EPB;
    const bool srt = (epay != nullptr);

    if (t >= 128 && t < 256) {
        winf_s[t - 128] = Winf[t - 128];
        wx2_s[t - 128] = Wx2[t - 128];
    } else if (t >= 256 && t < 320) {
        eij_acc[t - 256] = binf[0];
        xg_acc[t - 256] = 0.f;
    } else if (t == 320) {
        uint4 zf = {0u, 0u, 0u, 0u};
        *(uint4*)(zs + EPB * ZB) = zf;   // zero the overread slack
    }

    // Gather h[dst] -> z[0:128], h[src] -> z[128:256]; 8 lanes/edge, 64 edges.
    {
        int e = t >> 3, l = t & 7;
        unsigned short* zr = zs + e * ZB;
        if (srt) {
            uint4 pv = epay[e0 + e];
            const uint4* hd = (const uint4*)(hb + (size_t)pv.y * H);
            const uint4* hs = (const uint4*)(hb + (size_t)pv.x * H);
            uint4 a0 = hd[l * 2], a1 = hd[l * 2 + 1];
            *(uint4*)(zr + l * 16) = a0;
            *(uint4*)(zr + l * 16 + 8) = a1;
            uint4 c0 = hs[l * 2], c1 = hs[l * 2 + 1];
            *(uint4*)(zr + 128 + l * 16) = c0;
            *(uint4*)(zr + 128 + l * 16 + 8) = c1;
        } else {
            int s = ei[e0 + e], d = ei[NE + e0 + e];
            const float4* hd = (const float4*)(h + (size_t)d * H);
            const float4* hs = (const float4*)(h + (size_t)s * H);
            float4 v0 = hd[l * 4 + 0], v1 = hd[l * 4 + 1];
            float4 v2 = hd[l * 4 + 2], v3 = hd[l * 4 + 3];
            uint4 p0 = { pkbf(v0.x, v0.y), pkbf(v0.z, v0.w), pkbf(v1.x, v1.y), pkbf(v1.z, v1.w) };
            uint4 p1 = { pkbf(v2.x, v2.y), pkbf(v2.z, v2.w), pkbf(v3.x, v3.y), pkbf(v3.z, v3.w) };
            *(uint4*)(zr + l * 16) = p0;
            *(uint4*)(zr + l * 16 + 8) = p1;
            float4 w0 = hs[l * 4 + 0], w1 = hs[l * 4 + 1];
            float4 w2 = hs[l * 4 + 2], w3 = hs[l * 4 + 3];
            uint4 q0 = { pkbf(w0.x, w0.y), pkbf(w0.z, w0.w), pkbf(w1.x, w1.y), pkbf(w1.z, w1.w) };
            uint4 q1 = { pkbf(w2.x, w2.y), pkbf(w2.z, w2.w), pkbf(w3.x, w3.y), pkbf(w3.z, w3.w) };
            *(uint4*)(zr + 128 + l * 16) = q0;
            *(uint4*)(zr + 128 + l * 16 + 8) = q1;
        }
    }
    // Geometry + gaussians + edge_attr; 1 thread/edge.
    if (t < EPB) {
        unsigned short* zr = zs + t * ZB;
        int s, d;
        if (srt) {
            uint4 pv = epay[e0 + t];
            s = (int)pv.x; d = (int)pv.y;
            *(unsigned int*)(zr + 276) = pv.z;   // ea[0..1] bf16
            *(unsigned int*)(zr + 278) = pv.w;   // ea[2..3] bf16
        } else {
            s = ei[e0 + t]; d = ei[NE + e0 + t];
            #pragma unroll
            for (int j = 0; j < 4; j++)
                zr[276 + j] = f2bf(edge_attr[(size_t)(e0 + t) * 4 + j]);
        }
        dst_s[t] = d;
        float rx = x[d * 3 + 0] - x[s * 3 + 0];
        float ry = x[d * 3 + 1] - x[s * 3 + 1];
        float rz = x[d * 3 + 2] - x[s * 3 + 2];
        float d2 = rx * rx + ry * ry + rz * rz;
        float dd = sqrtf(d2 + 1e-8f);
        float inv = frcp(dd + 1.0f);
        relx_s[t][0] = rx * inv;
        relx_s[t][1] = ry * inv;
        relx_s[t][2] = rz * inv;
        const float step = 10.0f / 19.0f;
        const float coeff = -0.5f / (step * step);
        #pragma unroll
        for (int g = 0; g < 20; g++) {
            float df = dd - step * (float)g;
            zr[256 + g] = f2bf(__expf(coeff * df * df));
        }
    }
    __syncthreads();                                               // B

    const int wv = t >> 6, lane = t & 63;
    const int quad = lane >> 4, r16 = lane & 15;
    const int F = wv * 16;
    const int f0 = F + quad * 4;

    // Layer 1: (z @ We1)^T -> silu -> m1. 16 feat x 64 edges per wave.
    {
        f32x4 acc[4] = {};
        #pragma unroll
        for (int ks = 0; ks < KP1 / 32; ks++) {
            int ko = ks * 32 + quad * 8;
            u16x8 a = *(const u16x8*)(w1t + (size_t)(F + r16) * KP1 + ko);
            #pragma unroll
            for (int ci = 0; ci < 4; ci++) {
                u16x8 b = *(const u16x8*)(zs + (ci * 16 + r16) * ZB + ko);
                acc[ci] = mfma16(a, b, acc[ci]);
            }
        }
        __syncthreads();                                           // C
        float4 bv = *(const float4*)(be1 + f0);
        #pragma unroll
        for (int ci = 0; ci < 4; ci++) {
            int e = ci * 16 + r16;
            float s0 = silu_f(acc[ci][0] + bv.x);
            float s1 = silu_f(acc[ci][1] + bv.y);
            float s2 = silu_f(acc[ci][2] + bv.z);
            float s3 = silu_f(acc[ci][3] + bv.w);
            uint2 p = { pkbf(s0, s1), pkbf(s2, s3) };
            *(uint2*)(m1 + e * BB + f0) = p;
        }
    }
    __syncthreads();                                               // D

    // Layer 2: mij -> m2 (bf16). eij dot fused; partials via ds_add_f32.
    {
        f32x4 acc[4] = {};
        #pragma unroll
        for (int ks = 0; ks < H / 32; ks++) {
            int ko = ks * 32 + quad * 8;
            u16x8 a = *(const u16x8*)(w2t + (size_t)(F + r16) * H + ko);
            #pragma unroll
            for (int ci = 0; ci < 4; ci++) {
                u16x8 b = *(const u16x8*)(m1 + (ci * 16 + r16) * BB + ko);
                acc[ci] = mfma16(a, b, acc[ci]);
            }
        }
        float4 bv = *(const float4*)(be2 + f0);
        float4 wf = *(const float4*)(winf_s + f0);
        float ep[4];
        #pragma unroll
        for (int ci = 0; ci < 4; ci++) {
            int e = ci * 16 + r16;
            float s0 = silu_f(acc[ci][0] + bv.x);
            float s1 = silu_f(acc[ci][1] + bv.y);
            float s2 = silu_f(acc[ci][2] + bv.z);
            float s3 = silu_f(acc[ci][3] + bv.w);
            ep[ci] = s0 * wf.x + s1 * wf.y + s2 * wf.z + s3 * wf.w;
            uint2 p = { pkbf(s0, s1), pkbf(s2, s3) };
            *(uint2*)(m2 + e * BB + f0) = p;
        }
        #pragma unroll
        for (int ci = 0; ci < 4; ci++) {
            ep[ci] += __shfl_xor(ep[ci], 16, 64);
            ep[ci] += __shfl_xor(ep[ci], 32, 64);
        }
        if (quad == 0) {
            #pragma unroll
            for (int ci = 0; ci < 4; ci++)
                atomicAdd(&eij_acc[ci * 16 + r16], ep[ci]);
        }
    }
    __syncthreads();                                               // E

    // eij = sigmoid(acc); 64 threads, in place (ordered for segsum by F).
    if (t < EPB) eij_acc[t] = sigmoid_f(eij_acc[t]);

    // Coord layer: silu(mij @ Wx1) . Wx2, never materialized.
    {
        f32x4 acc[4] = {};
        #pragma unroll
        for (int ks = 0; ks < H / 32; ks++) {
            int ko = ks * 32 + quad * 8;
            u16x8 a = *(const u16x8*)(wx1t + (size_t)(F + r16) * H + ko);
            #pragma unroll
            for (int ci = 0; ci < 4; ci++) {
                u16x8 b = *(const u16x8*)(m2 + (ci * 16 + r16) * BB + ko);
                acc[ci] = mfma16(a, b, acc[ci]);
            }
        }
        float4 bv = *(const float4*)(bx1 + f0);
        float4 wf = *(const float4*)(wx2_s + f0);
        float xp[4];
        #pragma unroll
        for (int ci = 0; ci < 4; ci++) {
            xp[ci] = silu_f(acc[ci][0] + bv.x) * wf.x
                   + silu_f(acc[ci][1] + bv.y) * wf.y
                   + silu_f(acc[ci][2] + bv.z) * wf.z
                   + silu_f(acc[ci][3] + bv.w) * wf.w;
        }
        #pragma unroll
        for (int ci = 0; ci < 4; ci++) {
            xp[ci] += __shfl_xor(xp[ci], 16, 64);
            xp[ci] += __shfl_xor(xp[ci], 32, 64);
        }
        if (quad == 0) {
            #pragma unroll
            for (int ci = 0; ci < 4; ci++)
                atomicAdd(&xg_acc[ci * 16 + r16], xp[ci]);
        }
    }
    __syncthreads();                                               // F
    // (former barrier G removed: the 3 dx threads apply tanh inline below;
    //  all xg_acc ds_adds completed before F, eij sigmoid ordered by F.)

    // Segment sums over sorted runs: chunk-8 register prefetch breaks the
    // LDS-latency chain; one atomic per run; block-interior runs (dst wholly
    // owned, only in sorted mode) use a plain store.
    if (t < 128) {
        const int k = t;
        float acc = 0.f;
        int rs = 0;
        #pragma unroll
        for (int c = 0; c < EPB; c += 8) {
            float v[8];
            #pragma unroll
            for (int j = 0; j < 8; j++)
                v[j] = bf2f(m2[(c + j) * BB + k]) * eij_acc[c + j];
            #pragma unroll
            for (int j = 0; j < 8; j++) {
                int e = c + j;
                acc += v[j];
                if (e == EPB - 1 || dst_s[e + 1] != dst_s[e]) {
                    float* p = &mi[(size_t)dst_s[e] * H + k];
                    if (srt && rs > 0 && e < EPB - 1) *p = acc;
                    else atomicAdd(p, acc);
                    acc = 0.f;
                    rs = e + 1;
                }
            }
        }
    } else if (t < 131) {
        const int dd = t - 128;
        float acc = 0.f;
        int rs = 0;
        #pragma unroll
        for (int c = 0; c < EPB; c += 8) {
            float v[8];
            #pragma unroll
            for (int j = 0; j < 8; j++)
                v[j] = relx_s[c + j][dd] * tanh_f(xg_acc[c + j]);
            #pragma unroll
            for (int j = 0; j < 8; j++) {
                int e = c + j;
                acc += v[j];
                if (e == EPB - 1 || dst_s[e + 1] != dst_s[e]) {
                    float* p = &dx[(size_t)dst_s[e] * 3 + dd];
                    if (srt && rs > 0 && e < EPB - 1) *p = acc;
                    else atomicAdd(p, acc);
                    acc = 0.f;
                    rs = e + 1;
                }
            }
        }
    }
}

// ---------------- node kernel (bf16 MFMA, 512 thr, 64 nodes, R5) ------------
// 8 waves x 16feat x 64nodes: weight rows loaded by ONE wave per block.
// LDS ~33.8KB -> 4 blocks/CU. min-waves 6 (8 caused register-squeeze spills).
__global__ __launch_bounds__(512, 6) void node_kernel(
    const float* __restrict__ h, const float* __restrict__ x,
    const float* __restrict__ mask,
    const unsigned short* __restrict__ wn1t, const float* __restrict__ bn1,
    const unsigned short* __restrict__ wn2t, const float* __restrict__ bn2,
    const unsigned short* __restrict__ hb,
    float* __restrict__ mi_hout, float* __restrict__ dx_xout)
{
    __shared__ unsigned short nzs[NPB * NZB];   // 16896 shorts; nbuf needs 8704

    unsigned short* nbuf = nzs;

    const int t = threadIdx.x;
    const int n0 = blockIdx.x * NPB;

    {
        int r = t >> 3, l = t & 7;
        int n = n0 + r;
        unsigned short* zr = nzs + r * NZB;
        if (n < NN) {
            const float4* mi4 = (const float4*)(mi_hout + (size_t)n * H);
            float4 v0 = mi4[l * 4 + 0], v1 = mi4[l * 4 + 1];
            float4 v2 = mi4[l * 4 + 2], v3 = mi4[l * 4 + 3];
            uint4 p0 = { pkbf(v0.x, v0.y), pkbf(v0.z, v0.w), pkbf(v1.x, v1.y), pkbf(v1.z, v1.w) };
            uint4 p1 = { pkbf(v2.x, v2.y), pkbf(v2.z, v2.w), pkbf(v3.x, v3.y), pkbf(v3.z, v3.w) };
            *(uint4*)(zr + l * 16) = p0;
            *(uint4*)(zr + l * 16 + 8) = p1;
            if (hb) {
                const uint4* hs = (const uint4*)(hb + (size_t)n * H);
                *(uint4*)(zr + 128 + l * 16) = hs[l * 2];
                *(uint4*)(zr + 128 + l * 16 + 8) = hs[l * 2 + 1];
            } else {
                const float4* h4 = (const float4*)(h + (size_t)n * H);
                float4 w0 = h4[l * 4 + 0], w1 = h4[l * 4 + 1];
                float4 w2 = h4[l * 4 + 2], w3 = h4[l * 4 + 3];
                uint4 q0 = { pkbf(w0.x, w0.y), pkbf(w0.z, w0.w), pkbf(w1.x, w1.y), pkbf(w1.z, w1.w) };
                uint4 q1 = { pkbf(w2.x, w2.y), pkbf(w2.z, w2.w), pkbf(w3.x, w3.y), pkbf(w3.z, w3.w) };
                *(uint4*)(zr + 128 + l * 16) = q0;
                *(uint4*)(zr + 128 + l * 16 + 8) = q1;
            }
        } else {
            uint4 zf = {0u, 0u, 0u, 0u};
            *(uint4*)(zr + l * 16) = zf;
            *(uint4*)(zr + l * 16 + 8) = zf;
            *(uint4*)(zr + 128 + l * 16) = zf;
            *(uint4*)(zr + 128 + l * 16 + 8) = zf;
        }
    }

    float xo = 0.f;
    int xn = -1, xdim = 0;
    if (t < NPB * 3) {
        int r = t / 3; xdim = t % 3;
        int n = n0 + r;
        if (n < NN) {
            xn = n;
            xo = x[(size_t)n * 3 + xdim] + dx_xout[(size_t)n * 3 + xdim] * mask[n];
        }
    }
    __syncthreads();

    if (xn >= 0) dx_xout[(size_t)xn * 3 + xdim] = xo;

    const int wv = t >> 6, lane = t & 63;
    const int quad = lane >> 4, r16 = lane & 15;
    const int F = wv * 16;
    const int f0 = F + quad * 4;

    // n1: silu(nz @ Wn1) -> nbuf (aliases nzs). 16 feat x 64 nodes per wave.
    {
        f32x4 acc[4] = {};
        #pragma unroll
        for (int ks = 0; ks < 2 * H / 32; ks++) {
            int ko = ks * 32 + quad * 8;
            u16x8 a = *(const u16x8*)(wn1t + (size_t)(F + r16) * (2 * H) + ko);
            #pragma unroll
            for (int ci = 0; ci < 4; ci++) {
                u16x8 b = *(const u16x8*)(nzs + (ci * 16 + r16) * NZB + ko);
                acc[ci] = mfma16(a, b, acc[ci]);
            }
        }
        __syncthreads();
        float4 bv = *(const float4*)(bn1 + f0);
        #pragma unroll
        for (int ci = 0; ci < 4; ci++) {
            int e = ci * 16 + r16;
            float s0 = silu_f(acc[ci][0] + bv.x);
            float s1 = silu_f(acc[ci][1] + bv.y);
            float s2 = silu_f(acc[ci][2] + bv.z);
            float s3 = silu_f(acc[ci][3] + bv.w);
            uint2 p = { pkbf(s0, s1), pkbf(s2, s3) };
            *(uint2*)(nbuf + e * BB + f0) = p;
        }
    }
    __syncthreads();

    // n2: (nbuf @ Wn2) + bn2 + h -> h_out
    {
        f32x4 acc[4] = {};
        #pragma unroll
        for (int ks = 0; ks < H / 32; ks++) {
            int ko = ks * 32 + quad * 8;
            u16x8 a = *(const u16x8*)(wn2t + (size_t)(F + r16) * H + ko);
            #pragma unroll
            for (int ci = 0; ci < 4; ci++) {
                u16x8 b = *(const u16x8*)(nbuf + (ci * 16 + r16) * BB + ko);
                acc[ci] = mfma16(a, b, acc[ci]);
            }
        }
        float4 bv = *(const float4*)(bn2 + f0);
        #pragma unroll
        for (int ci = 0; ci < 4; ci++) {
            int n = n0 + ci * 16 + r16;
            if (n < NN) {
                float4 hv = *(const float4*)(h + (size_t)n * H + f0);
                float4 o;
                o.x = hv.x + acc[ci][0] + bv.x;
                o.y = hv.y + acc[ci][1] + bv.y;
                o.z = hv.z + acc[ci][2] + bv.z;
                o.w = hv.w + acc[ci][3] + bv.w;
                *(float4*)(mi_hout + (size_t)n * H + f0) = o;
            }
        }
    }
}

extern "C" void kernel_launch(void* const* d_in, const int* in_sizes, int n_in,
                              void* d_out, int out_size, void* d_ws, size_t ws_size,
                              hipStream_t stream) {
    const float* h     = (const float*)d_in[0];
    const float* x     = (const float*)d_in[1];
    const int*   ei    = (const int*)d_in[2];
    const float* mask  = (const float*)d_in[3];
    const float* eattr = (const float*)d_in[4];
    const float* We1   = (const float*)d_in[5];
    const float* be1   = (const float*)d_in[6];
    const float* We2   = (const float*)d_in[7];
    const float* be2   = (const float*)d_in[8];
    const float* Winf  = (const float*)d_in[9];
    const float* binf  = (const float*)d_in[10];
    const float* Wx1   = (const float*)d_in[11];
    const float* bx1   = (const float*)d_in[12];
    const float* Wx2   = (const float*)d_in[13];
    const float* Wn1   = (const float*)d_in[14];
    const float* bn1   = (const float*)d_in[15];
    const float* Wn2   = (const float*)d_in[16];
    const float* bn2   = (const float*)d_in[17];

    float* mi = (float*)d_out;
    float* dx = mi + (size_t)NN * H;

    // ws layout (bytes):
    //   [0, 256K)            bf16 weights (237568 used)
    //   [256K, +200704)      cnt   (NBPAD ints)
    //   [.., +16)            gtotal
    //   [.., +200704)        cur   (NBPAD ints)
    //   [.., +12.8M)         hb    (bf16 h)
    //   [.., +10.24M)        epay  (uint4 per edge, dst-sorted)
    char* wsb  = (char*)d_ws;
    unsigned short* w1t  = (unsigned short*)wsb;
    unsigned short* w2t  = w1t + 128 * KP1;
    unsigned short* wx1t = w2t + 128 * H;
    unsigned short* wn1t = wx1t + 128 * H;
    unsigned short* wn2t = wn1t + 128 * 256;

    const size_t OFF_CNT  = 262144;
    const size_t OFF_GTOT = OFF_CNT + (size_t)NBPAD * 4;     // 462848
    const size_t OFF_CUR  = OFF_GTOT + 16;                   // 462864
    const size_t OFF_HB   = OFF_CUR + (size_t)NBPAD * 4;     // 663568
    const size_t OFF_EPAY = OFF_HB + (size_t)NN * H * 2;     // 13463568
    const size_t WS_NEED  = OFF_EPAY + (size_t)NE * 16;      // 23703568

    int*   cnt  = (int*)(wsb + OFF_CNT);
    int*   gtot = (int*)(wsb + OFF_GTOT);
    int*   cur  = (int*)(wsb + OFF_CUR);
    unsigned short* hb = (unsigned short*)(wsb + OFF_HB);
    uint4* epay = (uint4*)(wsb + OFF_EPAY);

    const bool full = (ws_size >= WS_NEED);

    // K1 (full only): zero cnt + gtotal (must precede hist). 12545 float4s.
    if (full) {
        const int n4c = (int)((OFF_CUR - OFF_CNT) / 16);
        init_small_kernel<<<(n4c + 255) / 256, 256, 0, stream>>>(
            (float4*)(wsb + OFF_CNT), n4c);
    }

    // K2: hist || weight conv || zero d_out (co-run for overlap)
    {
        int hb_ = full ? HISTB : 0;
        hist_conv_zero_kernel<<<hb_ + CONVB + ZOB, 256, 0, stream>>>(
            ei, cnt, hb_, We1, We2, Wx1, Wn1, Wn2,
            w1t, w2t, wx1t, wn1t, wn2t, (float4*)d_out);
    }

    if (full) {
        // K3: run-base alloc (tiny)
        alloc_kernel<<<ALLOCB, 256, 0, stream>>>(cnt, cur, gtot);
        // K4: sorted payload scatter || h -> bf16
        scatter_hconv_kernel<<<NE / 256 + HCONVB, 256, 0, stream>>>(
            ei, eattr, cur, epay, h, hb);
    }

    edge_kernel<<<NE / EPB, 512, 0, stream>>>(
        h, x, ei, eattr, w1t, be1, w2t, be2, Winf, binf, wx1t, bx1, Wx2,
        full ? epay : (const uint4*)nullptr,
        full ? hb : (const unsigned short*)nullptr,
        mi, dx);

    node_kernel<<<(NN + NPB - 1) / NPB, 512, 0, stream>>>(
        h, x, mask, wn1t, bn1, wn2t, bn2,
        full ? hb : (const unsigned short*)nullptr,
        mi, dx);
}

// Round 8
// 425.908 us; speedup vs baseline: 1.2494x; 1.0420x over previous
//
#include <hip/hip_runtime.h>
#include <math.h>

#define NN 50000
#define NE 640000
#define H 128
#define EPB 64        // edges per block (512 threads, 8 waves x 16feat x 64edges)
#define NPB 64        // nodes per block (512 threads)
#define ZB 296        // LDS stride (bf16) for z rows (592 B) -- R3-proven
#define BB 136        // LDS stride (bf16) for 128-wide buffers (272 B)
#define KP1 288       // padded K for layer 1 (280 -> 288)
#define NZB 264       // LDS stride (bf16) for node 256-wide input (528 B)
#define NBPAD 50176   // 50000 rounded up to 256*196
#define HISTB (NE / 256)      // 2500
#define CONVB 464             // 118784 weight elems / 256
#define ALLOCB (NBPAD / 256)  // 196
#define HCONVB 3125           // 800000 ushort8-groups / 256
#define N4OUT ((NN * H + NN * 3) / 4)          // 1637500 float4 of d_out
#define ZOB ((N4OUT + 255) / 256)              // 6397 zero blocks

typedef __attribute__((ext_vector_type(8))) unsigned short u16x8;
typedef __attribute__((ext_vector_type(8))) __bf16 bf16x8;
typedef __attribute__((ext_vector_type(2))) __bf16 bf16x2;
typedef __attribute__((ext_vector_type(4))) float f32x4;

__device__ __forceinline__ float frcp(float x) {
#if __has_builtin(__builtin_amdgcn_rcpf)
    return __builtin_amdgcn_rcpf(x);   // raw v_rcp_f32, no Newton refine
#else
    return 1.0f / x;
#endif
}

__device__ __forceinline__ float silu_f(float v) {
    return v * frcp(1.0f + __expf(-v));
}

__device__ __forceinline__ float sigmoid_f(float v) {
    return frcp(1.0f + __expf(-v));
}

__device__ __forceinline__ float tanh_f(float v) {
    // tanh(x) = 1 - 2/(e^{2x}+1); exact at +-inf, fine for |err|~1e-6
    return 1.0f - 2.0f * frcp(1.0f + __expf(2.0f * v));
}

__device__ __forceinline__ unsigned short f2bf(float f) {
    unsigned int u = __builtin_bit_cast(unsigned int, f);
    u += 0x7FFFu + ((u >> 16) & 1u);   // RNE
    return (unsigned short)(u >> 16);
}

__device__ __forceinline__ float bf2f(unsigned short s) {
    unsigned int u = ((unsigned int)s) << 16;
    return __builtin_bit_cast(float, u);
}

__device__ __forceinline__ unsigned int pkbf(float lo, float hi) {
#if __has_builtin(__builtin_amdgcn_cvt_pk_bf16_f32)
    bf16x2 v = __builtin_amdgcn_cvt_pk_bf16_f32(lo, hi);
    unsigned int r; __builtin_memcpy(&r, &v, 4); return r;
#else
    return (unsigned int)f2bf(lo) | ((unsigned int)f2bf(hi) << 16);
#endif
}

__device__ __forceinline__ f32x4 mfma16(u16x8 a, u16x8 b, f32x4 c) {
    return __builtin_amdgcn_mfma_f32_16x16x32_bf16(
        __builtin_bit_cast(bf16x8, a), __builtin_bit_cast(bf16x8, b), c, 0, 0, 0);
}

// ---------------- K1: zero cnt + gtotal (tiny; must precede hist) -----------
__global__ __launch_bounds__(256) void init_small_kernel(
    float4* __restrict__ p, int n4)
{
    int i = blockIdx.x * 256 + threadIdx.x;
    if (i < n4) p[i] = make_float4(0.f, 0.f, 0.f, 0.f);
}

// ---------------- K2: hist || weight conv || zero d_out || h -> bf16 --------
__global__ __launch_bounds__(256) void hist_conv_zero_hconv_kernel(
    const int* __restrict__ ei, int* __restrict__ cnt, int histBlocks,
    const float* __restrict__ We1, const float* __restrict__ We2,
    const float* __restrict__ Wx1, const float* __restrict__ Wn1,
    const float* __restrict__ Wn2,
    unsigned short* __restrict__ w1t, unsigned short* __restrict__ w2t,
    unsigned short* __restrict__ wx1t, unsigned short* __restrict__ wn1t,
    unsigned short* __restrict__ wn2t,
    float4* __restrict__ out4,
    const float* __restrict__ h, unsigned short* __restrict__ hb)
{
    int b = blockIdx.x, t = threadIdx.x;
    if (b < histBlocks) {
        atomicAdd(&cnt[ei[NE + b * 256 + t]], 1);
        return;
    }
    b -= histBlocks;
    if (b < CONVB) {
        int i = b * 256 + t;
        const int S1 = 128 * KP1;
        const int S2 = 128 * 128;
        const int S3 = 128 * 256;
        if (i < S1) {
            int n = i / KP1, k = i % KP1;
            w1t[i] = (k < 280) ? f2bf(We1[k * H + n]) : (unsigned short)0;
        } else if (i < S1 + S2) {
            int j = i - S1; int n = j / H, k = j % H;
            w2t[j] = f2bf(We2[k * H + n]);
        } else if (i < S1 + 2 * S2) {
            int j = i - S1 - S2; int n = j / H, k = j % H;
            wx1t[j] = f2bf(Wx1[k * H + n]);
        } else if (i < S1 + 2 * S2 + S3) {
            int j = i - S1 - 2 * S2; int n = j / 256, k = j % 256;
            wn1t[j] = f2bf(Wn1[k * H + n]);
        } else if (i < S1 + 3 * S2 + S3) {
            int j = i - S1 - 2 * S2 - S3; int n = j / H, k = j % H;
            wn2t[j] = f2bf(Wn2[k * H + n]);
        }
        return;
    }
    b -= CONVB;
    if (b < ZOB) {
        int i = b * 256 + t;
        if (i < N4OUT) out4[i] = make_float4(0.f, 0.f, 0.f, 0.f);
        return;
    }
    b -= ZOB;
    int j = b * 256 + t;                  // j < 800000, 8 floats each
    const float4* hp = (const float4*)h + (size_t)j * 2;
    float4 a = hp[0], c = hp[1];
    uint4 pk = { pkbf(a.x, a.y), pkbf(a.z, a.w), pkbf(c.x, c.y), pkbf(c.z, c.w) };
    ((uint4*)hb)[j] = pk;
}

// ---------------- K3: run-base allocation (no scan) -------------------------
// Group order is irrelevant for the segment sum; each dst just needs a
// contiguous slice. Wave-scan cnt, one global atomicAdd per wave.
__global__ __launch_bounds__(256) void alloc_kernel(
    const int* __restrict__ cnt, int* __restrict__ cur, int* __restrict__ gtot)
{
    int t = threadIdx.x;
    int d = blockIdx.x * 256 + t;
    int v = cnt[d];
    int incl = v;
    #pragma unroll
    for (int o = 1; o < 64; o <<= 1) {
        int u = __shfl_up(incl, o, 64);
        if ((t & 63) >= o) incl += u;
    }
    int total = __shfl(incl, 63, 64);
    int base = 0;
    if ((t & 63) == 63) base = atomicAdd(gtot, total);
    base = __shfl(base, 63, 64);
    cur[d] = base + incl - v;
}

// ---------------- K4: scatter sorted payload {src, dst, ea bf16x4} ----------
__global__ __launch_bounds__(256) void scatter_kernel(
    const int* __restrict__ ei, const float* __restrict__ edge_attr,
    int* __restrict__ cur, uint4* __restrict__ epay)
{
    int i = blockIdx.x * 256 + threadIdx.x;
    int s = ei[i], d = ei[NE + i];
    float4 ea = ((const float4*)edge_attr)[i];
    int p = atomicAdd(&cur[d], 1);
    uint4 pv = { (unsigned)s, (unsigned)d, pkbf(ea.x, ea.y), pkbf(ea.z, ea.w) };
    epay[p] = pv;
}

// ---------------- edge kernel (R3 body + XCD swizzle) -----------------------
// 512 threads, 8 waves x 16feat x 64edges: each weight line touched by ONE
// wave per block. Partial reductions via epart/xpart ARRAYS (plain stores +
// 8-way sum) -- the ds_add_f32 variant (R4/R5) serialized 8-way on the DS
// pipe and cost ~6% despite higher occupancy. LDS 44544B -> 3 blocks/CU
// (24 waves); R3 measured faster at this occupancy than the 32-wave diet.
// min-waves 6 ((512,8) forced a 32-VGPR spill, R4).
__global__ __launch_bounds__(512, 6) void edge_kernel(
    const float* __restrict__ h, const float* __restrict__ x,
    const int* __restrict__ ei, const float* __restrict__ edge_attr,
    const unsigned short* __restrict__ w1t, const float* __restrict__ be1,
    const unsigned short* __restrict__ w2t, const float* __restrict__ be2,
    const float* __restrict__ Winf, const float* __restrict__ binf,
    const unsigned short* __restrict__ wx1t, const float* __restrict__ bx1,
    const float* __restrict__ Wx2,
    const uint4* __restrict__ epay, const unsigned short* __restrict__ hb,
    float* __restrict__ mi, float* __restrict__ dx)
{
    // zs dead after L1 K-loop: m1 aliases zs[0:EPB*BB], m2 the next EPB*BB
    // (2*EPB*BB = 17408 shorts <= EPB*ZB = 18944).
    __shared__ unsigned short zs[EPB * ZB];
    __shared__ float relx_s[EPB][3];
    __shared__ float eij_s[EPB];
    __shared__ float xg_s[EPB];
    __shared__ float epart[8][EPB];
    __shared__ float xpart[8][EPB];
    __shared__ int dst_s[EPB];
    __shared__ float winf_s[H];
    __shared__ float wx2_s[H];

    unsigned short* m1 = zs;
    unsigned short* m2 = zs + EPB * BB;

    const int t = threadIdx.x;
    // XCD-chunked bijective swizzle (gridDim.x % 8 == 0 for NE/EPB = 10000):
    // dst-sorted neighbor blocks land on the same XCD L2.
    int bid = blockIdx.x;
    if ((gridDim.x & 7) == 0) {
        int cpx = gridDim.x >> 3;
        bid = (bid & 7) * cpx + (bid >> 3);
    }
    const int e0 = bid * EPB;
    const bool srt = (epay != nullptr);

    if (t >= 128 && t < 256) {
        winf_s[t - 128] = Winf[t - 128];
        wx2_s[t - 128] = Wx2[t - 128];
    }

    // Gather h[dst] -> z[0:128], h[src] -> z[128:256]; 8 lanes/edge, 64 edges.
    {
        int e = t >> 3, l = t & 7;
        unsigned short* zr = zs + e * ZB;
        if (srt) {
            uint4 pv = epay[e0 + e];
            const uint4* hd = (const uint4*)(hb + (size_t)pv.y * H);
            const uint4* hs = (const uint4*)(hb + (size_t)pv.x * H);
            uint4 a0 = hd[l * 2], a1 = hd[l * 2 + 1];
            *(uint4*)(zr + l * 16) = a0;
            *(uint4*)(zr + l * 16 + 8) = a1;
            uint4 c0 = hs[l * 2], c1 = hs[l * 2 + 1];
            *(uint4*)(zr + 128 + l * 16) = c0;
            *(uint4*)(zr + 128 + l * 16 + 8) = c1;
        } else {
            int s = ei[e0 + e], d = ei[NE + e0 + e];
            const float4* hd = (const float4*)(h + (size_t)d * H);
            const float4* hs = (const float4*)(h + (size_t)s * H);
            float4 v0 = hd[l * 4 + 0], v1 = hd[l * 4 + 1];
            float4 v2 = hd[l * 4 + 2], v3 = hd[l * 4 + 3];
            uint4 p0 = { pkbf(v0.x, v0.y), pkbf(v0.z, v0.w), pkbf(v1.x, v1.y), pkbf(v1.z, v1.w) };
            uint4 p1 = { pkbf(v2.x, v2.y), pkbf(v2.z, v2.w), pkbf(v3.x, v3.y), pkbf(v3.z, v3.w) };
            *(uint4*)(zr + l * 16) = p0;
            *(uint4*)(zr + l * 16 + 8) = p1;
            float4 w0 = hs[l * 4 + 0], w1 = hs[l * 4 + 1];
            float4 w2 = hs[l * 4 + 2], w3 = hs[l * 4 + 3];
            uint4 q0 = { pkbf(w0.x, w0.y), pkbf(w0.z, w0.w), pkbf(w1.x, w1.y), pkbf(w1.z, w1.w) };
            uint4 q1 = { pkbf(w2.x, w2.y), pkbf(w2.z, w2.w), pkbf(w3.x, w3.y), pkbf(w3.z, w3.w) };
            *(uint4*)(zr + 128 + l * 16) = q0;
            *(uint4*)(zr + 128 + l * 16 + 8) = q1;
        }
    }
    // Geometry + gaussians + edge_attr + pad; 1 thread/edge.
    if (t < EPB) {
        unsigned short* zr = zs + t * ZB;
        int s, d;
        if (srt) {
            uint4 pv = epay[e0 + t];
            s = (int)pv.x; d = (int)pv.y;
            *(unsigned int*)(zr + 276) = pv.z;   // ea[0..1] bf16
            *(unsigned int*)(zr + 278) = pv.w;   // ea[2..3] bf16
        } else {
            s = ei[e0 + t]; d = ei[NE + e0 + t];
            #pragma unroll
            for (int j = 0; j < 4; j++)
                zr[276 + j] = f2bf(edge_attr[(size_t)(e0 + t) * 4 + j]);
        }
        dst_s[t] = d;
        float rx = x[d * 3 + 0] - x[s * 3 + 0];
        float ry = x[d * 3 + 1] - x[s * 3 + 1];
        float rz = x[d * 3 + 2] - x[s * 3 + 2];
        float d2 = rx * rx + ry * ry + rz * rz;
        float dd = sqrtf(d2 + 1e-8f);
        float inv = frcp(dd + 1.0f);
        relx_s[t][0] = rx * inv;
        relx_s[t][1] = ry * inv;
        relx_s[t][2] = rz * inv;
        const float step = 10.0f / 19.0f;
        const float coeff = -0.5f / (step * step);
        #pragma unroll
        for (int g = 0; g < 20; g++) {
            float df = dd - step * (float)g;
            zr[256 + g] = f2bf(__expf(coeff * df * df));
        }
        #pragma unroll
        for (int j = 280; j < ZB; j++) zr[j] = 0;
    }
    __syncthreads();                                               // B

    const int wv = t >> 6, lane = t & 63;
    const int quad = lane >> 4, r16 = lane & 15;
    const int F = wv * 16;
    const int f0 = F + quad * 4;

    // Layer 1: (z @ We1)^T -> silu -> m1. 16 feat x 64 edges per wave.
    {
        f32x4 acc[4] = {};
        #pragma unroll
        for (int ks = 0; ks < KP1 / 32; ks++) {
            int ko = ks * 32 + quad * 8;
            u16x8 a = *(const u16x8*)(w1t + (size_t)(F + r16) * KP1 + ko);
            #pragma unroll
            for (int ci = 0; ci < 4; ci++) {
                u16x8 b = *(const u16x8*)(zs + (ci * 16 + r16) * ZB + ko);
                acc[ci] = mfma16(a, b, acc[ci]);
            }
        }
        __syncthreads();                                           // C
        float4 bv = *(const float4*)(be1 + f0);
        #pragma unroll
        for (int ci = 0; ci < 4; ci++) {
            int e = ci * 16 + r16;
            float s0 = silu_f(acc[ci][0] + bv.x);
            float s1 = silu_f(acc[ci][1] + bv.y);
            float s2 = silu_f(acc[ci][2] + bv.z);
            float s3 = silu_f(acc[ci][3] + bv.w);
            uint2 p = { pkbf(s0, s1), pkbf(s2, s3) };
            *(uint2*)(m1 + e * BB + f0) = p;
        }
    }
    __syncthreads();                                               // D

    // Layer 2: mij -> m2 (bf16). eij dot fused; partials to epart array.
    {
        f32x4 acc[4] = {};
        #pragma unroll
        for (int ks = 0; ks < H / 32; ks++) {
            int ko = ks * 32 + quad * 8;
            u16x8 a = *(const u16x8*)(w2t + (size_t)(F + r16) * H + ko);
            #pragma unroll
            for (int ci = 0; ci < 4; ci++) {
                u16x8 b = *(const u16x8*)(m1 + (ci * 16 + r16) * BB + ko);
                acc[ci] = mfma16(a, b, acc[ci]);
            }
        }
        float4 bv = *(const float4*)(be2 + f0);
        float4 wf = *(const float4*)(winf_s + f0);
        float ep[4];
        #pragma unroll
        for (int ci = 0; ci < 4; ci++) {
            int e = ci * 16 + r16;
            float s0 = silu_f(acc[ci][0] + bv.x);
            float s1 = silu_f(acc[ci][1] + bv.y);
            float s2 = silu_f(acc[ci][2] + bv.z);
            float s3 = silu_f(acc[ci][3] + bv.w);
            ep[ci] = s0 * wf.x + s1 * wf.y + s2 * wf.z + s3 * wf.w;
            uint2 p = { pkbf(s0, s1), pkbf(s2, s3) };
            *(uint2*)(m2 + e * BB + f0) = p;
        }
        #pragma unroll
        for (int ci = 0; ci < 4; ci++) {
            ep[ci] += __shfl_xor(ep[ci], 16, 64);
            ep[ci] += __shfl_xor(ep[ci], 32, 64);
        }
        if (quad == 0) {
            #pragma unroll
            for (int ci = 0; ci < 4; ci++)
                epart[wv][ci * 16 + r16] = ep[ci];
        }
    }
    __syncthreads();                                               // E

    // eij = sigmoid(sum + binf); 64 threads. (Ordered for segsum by F.)
    if (t < EPB) {
        float s = binf[0];
        #pragma unroll
        for (int w = 0; w < 8; w++) s += epart[w][t];
        eij_s[t] = sigmoid_f(s);
    }

    // Coord layer: silu(mij @ Wx1) . Wx2, never materialized.
    {
        f32x4 acc[4] = {};
        #pragma unroll
        for (int ks = 0; ks < H / 32; ks++) {
            int ko = ks * 32 + quad * 8;
            u16x8 a = *(const u16x8*)(wx1t + (size_t)(F + r16) * H + ko);
            #pragma unroll
            for (int ci = 0; ci < 4; ci++) {
                u16x8 b = *(const u16x8*)(m2 + (ci * 16 + r16) * BB + ko);
                acc[ci] = mfma16(a, b, acc[ci]);
            }
        }
        float4 bv = *(const float4*)(bx1 + f0);
        float4 wf = *(const float4*)(wx2_s + f0);
        float xp[4];
        #pragma unroll
        for (int ci = 0; ci < 4; ci++) {
            xp[ci] = silu_f(acc[ci][0] + bv.x) * wf.x
                   + silu_f(acc[ci][1] + bv.y) * wf.y
                   + silu_f(acc[ci][2] + bv.z) * wf.z
                   + silu_f(acc[ci][3] + bv.w) * wf.w;
        }
        #pragma unroll
        for (int ci = 0; ci < 4; ci++) {
            xp[ci] += __shfl_xor(xp[ci], 16, 64);
            xp[ci] += __shfl_xor(xp[ci], 32, 64);
        }
        if (quad == 0) {
            #pragma unroll
            for (int ci = 0; ci < 4; ci++)
                xpart[wv][ci * 16 + r16] = xp[ci];
        }
    }
    __syncthreads();                                               // F

    // xg = tanh(sum of partials); 64 threads, then barrier for the 3-thread
    // dx run-accumulation.
    if (t < EPB) {
        float xs = 0.f;
        #pragma unroll
        for (int w = 0; w < 8; w++) xs += xpart[w][t];
        xg_s[t] = tanh_f(xs);
    }
    __syncthreads();                                               // G

    // Segment sums over sorted runs: chunk-8 register prefetch breaks the
    // LDS-latency chain; one atomic per run; block-interior runs (dst wholly
    // owned, only in sorted mode) use a plain store.
    if (t < 128) {
        const int k = t;
        float acc = 0.f;
        int rs = 0;
        #pragma unroll
        for (int c = 0; c < EPB; c += 8) {
            float v[8];
            #pragma unroll
            for (int j = 0; j < 8; j++)
                v[j] = bf2f(m2[(c + j) * BB + k]) * eij_s[c + j];
            #pragma unroll
            for (int j = 0; j < 8; j++) {
                int e = c + j;
                acc += v[j];
                if (e == EPB - 1 || dst_s[e + 1] != dst_s[e]) {
                    float* p = &mi[(size_t)dst_s[e] * H + k];
                    if (srt && rs > 0 && e < EPB - 1) *p = acc;
                    else atomicAdd(p, acc);
                    acc = 0.f;
                    rs = e + 1;
                }
            }
        }
    } else if (t < 131) {
        const int dd = t - 128;
        float acc = 0.f;
        int rs = 0;
        #pragma unroll
        for (int c = 0; c < EPB; c += 8) {
            float v[8];
            #pragma unroll
            for (int j = 0; j < 8; j++)
                v[j] = relx_s[c + j][dd] * xg_s[c + j];
            #pragma unroll
            for (int j = 0; j < 8; j++) {
                int e = c + j;
                acc += v[j];
                if (e == EPB - 1 || dst_s[e + 1] != dst_s[e]) {
                    float* p = &dx[(size_t)dst_s[e] * 3 + dd];
                    if (srt && rs > 0 && e < EPB - 1) *p = acc;
                    else atomicAdd(p, acc);
                    acc = 0.f;
                    rs = e + 1;
                }
            }
        }
    }
}

// ---------------- node kernel (bf16 MFMA, 512 thr, 64 nodes) ----------------
// 8 waves x 16feat x 64nodes: weight rows loaded by ONE wave per block.
// LDS ~33.8KB -> 4 blocks/CU. min-waves 6 (8 caused register-squeeze spills).
__global__ __launch_bounds__(512, 6) void node_kernel(
    const float* __restrict__ h, const float* __restrict__ x,
    const float* __restrict__ mask,
    const unsigned short* __restrict__ wn1t, const float* __restrict__ bn1,
    const unsigned short* __restrict__ wn2t, const float* __restrict__ bn2,
    const unsigned short* __restrict__ hb,
    float* __restrict__ mi_hout, float* __restrict__ dx_xout)
{
    __shared__ unsigned short nzs[NPB * NZB];   // 16896 shorts; nbuf needs 8704

    unsigned short* nbuf = nzs;

    const int t = threadIdx.x;
    const int n0 = blockIdx.x * NPB;

    {
        int r = t >> 3, l = t & 7;
        int n = n0 + r;
        unsigned short* zr = nzs + r * NZB;
        if (n < NN) {
            const float4* mi4 = (const float4*)(mi_hout + (size_t)n * H);
            float4 v0 = mi4[l * 4 + 0], v1 = mi4[l * 4 + 1];
            float4 v2 = mi4[l * 4 + 2], v3 = mi4[l * 4 + 3];
            uint4 p0 = { pkbf(v0.x, v0.y), pkbf(v0.z, v0.w), pkbf(v1.x, v1.y), pkbf(v1.z, v1.w) };
            uint4 p1 = { pkbf(v2.x, v2.y), pkbf(v2.z, v2.w), pkbf(v3.x, v3.y), pkbf(v3.z, v3.w) };
            *(uint4*)(zr + l * 16) = p0;
            *(uint4*)(zr + l * 16 + 8) = p1;
            if (hb) {
                const uint4* hs = (const uint4*)(hb + (size_t)n * H);
                *(uint4*)(zr + 128 + l * 16) = hs[l * 2];
                *(uint4*)(zr + 128 + l * 16 + 8) = hs[l * 2 + 1];
            } else {
                const float4* h4 = (const float4*)(h + (size_t)n * H);
                float4 w0 = h4[l * 4 + 0], w1 = h4[l * 4 + 1];
                float4 w2 = h4[l * 4 + 2], w3 = h4[l * 4 + 3];
                uint4 q0 = { pkbf(w0.x, w0.y), pkbf(w0.z, w0.w), pkbf(w1.x, w1.y), pkbf(w1.z, w1.w) };
                uint4 q1 = { pkbf(w2.x, w2.y), pkbf(w2.z, w2.w), pkbf(w3.x, w3.y), pkbf(w3.z, w3.w) };
                *(uint4*)(zr + 128 + l * 16) = q0;
                *(uint4*)(zr + 128 + l * 16 + 8) = q1;
            }
        } else {
            uint4 zf = {0u, 0u, 0u, 0u};
            *(uint4*)(zr + l * 16) = zf;
            *(uint4*)(zr + l * 16 + 8) = zf;
            *(uint4*)(zr + 128 + l * 16) = zf;
            *(uint4*)(zr + 128 + l * 16 + 8) = zf;
        }
    }

    float xo = 0.f;
    int xn = -1, xdim = 0;
    if (t < NPB * 3) {
        int r = t / 3; xdim = t % 3;
        int n = n0 + r;
        if (n < NN) {
            xn = n;
            xo = x[(size_t)n * 3 + xdim] + dx_xout[(size_t)n * 3 + xdim] * mask[n];
        }
    }
    __syncthreads();

    if (xn >= 0) dx_xout[(size_t)xn * 3 + xdim] = xo;

    const int wv = t >> 6, lane = t & 63;
    const int quad = lane >> 4, r16 = lane & 15;
    const int F = wv * 16;
    const int f0 = F + quad * 4;

    // n1: silu(nz @ Wn1) -> nbuf (aliases nzs). 16 feat x 64 nodes per wave.
    {
        f32x4 acc[4] = {};
        #pragma unroll
        for (int ks = 0; ks < 2 * H / 32; ks++) {
            int ko = ks * 32 + quad * 8;
            u16x8 a = *(const u16x8*)(wn1t + (size_t)(F + r16) * (2 * H) + ko);
            #pragma unroll
            for (int ci = 0; ci < 4; ci++) {
                u16x8 b = *(const u16x8*)(nzs + (ci * 16 + r16) * NZB + ko);
                acc[ci] = mfma16(a, b, acc[ci]);
            }
        }
        __syncthreads();
        float4 bv = *(const float4*)(bn1 + f0);
        #pragma unroll
        for (int ci = 0; ci < 4; ci++) {
            int e = ci * 16 + r16;
            float s0 = silu_f(acc[ci][0] + bv.x);
            float s1 = silu_f(acc[ci][1] + bv.y);
            float s2 = silu_f(acc[ci][2] + bv.z);
            float s3 = silu_f(acc[ci][3] + bv.w);
            uint2 p = { pkbf(s0, s1), pkbf(s2, s3) };
            *(uint2*)(nbuf + e * BB + f0) = p;
        }
    }
    __syncthreads();

    // n2: (nbuf @ Wn2) + bn2 + h -> h_out
    {
        f32x4 acc[4] = {};
        #pragma unroll
        for (int ks = 0; ks < H / 32; ks++) {
            int ko = ks * 32 + quad * 8;
            u16x8 a = *(const u16x8*)(wn2t + (size_t)(F + r16) * H + ko);
            #pragma unroll
            for (int ci = 0; ci < 4; ci++) {
                u16x8 b = *(const u16x8*)(nbuf + (ci * 16 + r16) * BB + ko);
                acc[ci] = mfma16(a, b, acc[ci]);
            }
        }
        float4 bv = *(const float4*)(bn2 + f0);
        #pragma unroll
        for (int ci = 0; ci < 4; ci++) {
            int n = n0 + ci * 16 + r16;
            if (n < NN) {
                float4 hv = *(const float4*)(h + (size_t)n * H + f0);
                float4 o;
                o.x = hv.x + acc[ci][0] + bv.x;
                o.y = hv.y + acc[ci][1] + bv.y;
                o.z = hv.z + acc[ci][2] + bv.z;
                o.w = hv.w + acc[ci][3] + bv.w;
                *(float4*)(mi_hout + (size_t)n * H + f0) = o;
            }
        }
    }
}

extern "C" void kernel_launch(void* const* d_in, const int* in_sizes, int n_in,
                              void* d_out, int out_size, void* d_ws, size_t ws_size,
                              hipStream_t stream) {
    const float* h     = (const float*)d_in[0];
    const float* x     = (const float*)d_in[1];
    const int*   ei    = (const int*)d_in[2];
    const float* mask  = (const float*)d_in[3];
    const float* eattr = (const float*)d_in[4];
    const float* We1   = (const float*)d_in[5];
    const float* be1   = (const float*)d_in[6];
    const float* We2   = (const float*)d_in[7];
    const float* be2   = (const float*)d_in[8];
    const float* Winf  = (const float*)d_in[9];
    const float* binf  = (const float*)d_in[10];
    const float* Wx1   = (const float*)d_in[11];
    const float* bx1   = (const float*)d_in[12];
    const float* Wx2   = (const float*)d_in[13];
    const float* Wn1   = (const float*)d_in[14];
    const float* bn1   = (const float*)d_in[15];
    const float* Wn2   = (const float*)d_in[16];
    const float* bn2   = (const float*)d_in[17];

    float* mi = (float*)d_out;
    float* dx = mi + (size_t)NN * H;

    // ws layout (bytes):
    //   [0, 256K)            bf16 weights (237568 used)
    //   [256K, +200704)      cnt   (NBPAD ints)
    //   [.., +16)            gtotal
    //   [.., +200704)        cur   (NBPAD ints)
    //   [.., +12.8M)         hb    (bf16 h)
    //   [.., +10.24M)        epay  (uint4 per edge, dst-sorted)
    char* wsb  = (char*)d_ws;
    unsigned short* w1t  = (unsigned short*)wsb;
    unsigned short* w2t  = w1t + 128 * KP1;
    unsigned short* wx1t = w2t + 128 * H;
    unsigned short* wn1t = wx1t + 128 * H;
    unsigned short* wn2t = wn1t + 128 * 256;

    const size_t OFF_CNT  = 262144;
    const size_t OFF_GTOT = OFF_CNT + (size_t)NBPAD * 4;     // 462848
    const size_t OFF_CUR  = OFF_GTOT + 16;                   // 462864
    const size_t OFF_HB   = OFF_CUR + (size_t)NBPAD * 4;     // 663568
    const size_t OFF_EPAY = OFF_HB + (size_t)NN * H * 2;     // 13463568
    const size_t WS_NEED  = OFF_EPAY + (size_t)NE * 16;      // 23703568

    int*   cnt  = (int*)(wsb + OFF_CNT);
    int*   gtot = (int*)(wsb + OFF_GTOT);
    int*   cur  = (int*)(wsb + OFF_CUR);
    unsigned short* hb = (unsigned short*)(wsb + OFF_HB);
    uint4* epay = (uint4*)(wsb + OFF_EPAY);

    const bool full = (ws_size >= WS_NEED);

    // K1 (full only): zero cnt + gtotal (must precede hist). 12545 float4s.
    if (full) {
        const int n4c = (int)((OFF_CUR - OFF_CNT) / 16);
        init_small_kernel<<<(n4c + 255) / 256, 256, 0, stream>>>(
            (float4*)(wsb + OFF_CNT), n4c);
    }

    // K2: hist || weight conv || zero d_out || h->bf16 (co-run for overlap)
    {
        int hb_ = full ? HISTB : 0;
        int hc_ = full ? HCONVB : 0;
        hist_conv_zero_hconv_kernel<<<hb_ + CONVB + ZOB + hc_, 256, 0, stream>>>(
            ei, cnt, hb_, We1, We2, Wx1, Wn1, Wn2,
            w1t, w2t, wx1t, wn1t, wn2t, (float4*)d_out, h, hb);
    }

    if (full) {
        // K3: run-base alloc (tiny)
        alloc_kernel<<<ALLOCB, 256, 0, stream>>>(cnt, cur, gtot);
        // K4: sorted payload scatter
        scatter_kernel<<<NE / 256, 256, 0, stream>>>(ei, eattr, cur, epay);
    }

    edge_kernel<<<NE / EPB, 512, 0, stream>>>(
        h, x, ei, eattr, w1t, be1, w2t, be2, Winf, binf, wx1t, bx1, Wx2,
        full ? epay : (const uint4*)nullptr,
        full ? hb : (const unsigned short*)nullptr,
        mi, dx);

    node_kernel<<<(NN + NPB - 1) / NPB, 512, 0, stream>>>(
        h, x, mask, wn1t, bn1, wn2t, bn2,
        full ? hb : (const unsigned short*)nullptr,
        mi, dx);
}

// Round 9
// 424.777 us; speedup vs baseline: 1.2528x; 1.0027x over previous
//
#include <hip/hip_runtime.h>
#include <math.h>

#define NN 50000
#define NE 640000
#define H 128
#define EPB 64        // edges per block (512 threads, 8 waves x 16feat x 64edges)
#define NPB 64        // nodes per block (512 threads)
#define ZB 296        // LDS stride (bf16) for z rows (592 B) -- R3-proven
#define BB 136        // LDS stride (bf16) for 128-wide buffers (272 B)
#define KP1 288       // padded K for layer 1 (280 -> 288)
#define NZB 264       // LDS stride (bf16) for node 256-wide input (528 B)
#define NBPAD 50176   // 50000 rounded up to 256*196
#define HISTB (NE / 256)      // 2500
#define CONVB 464             // 118784 weight elems / 256
#define ALLOCB (NBPAD / 256)  // 196
#define HCONVB 3125           // 800000 ushort8-groups / 256
#define N4OUT ((NN * H + NN * 3) / 4)          // 1637500 float4 of d_out
#define ZOB ((N4OUT + 255) / 256)              // 6397 zero blocks

typedef __attribute__((ext_vector_type(8))) unsigned short u16x8;
typedef __attribute__((ext_vector_type(8))) __bf16 bf16x8;
typedef __attribute__((ext_vector_type(2))) __bf16 bf16x2;
typedef __attribute__((ext_vector_type(4))) float f32x4;

__device__ __forceinline__ float frcp(float x) {
#if __has_builtin(__builtin_amdgcn_rcpf)
    return __builtin_amdgcn_rcpf(x);   // raw v_rcp_f32, no Newton refine
#else
    return 1.0f / x;
#endif
}

__device__ __forceinline__ float silu_f(float v) {
    return v * frcp(1.0f + __expf(-v));
}

__device__ __forceinline__ float sigmoid_f(float v) {
    return frcp(1.0f + __expf(-v));
}

__device__ __forceinline__ float tanh_f(float v) {
    // tanh(x) = 1 - 2/(e^{2x}+1); exact at +-inf, fine for |err|~1e-6
    return 1.0f - 2.0f * frcp(1.0f + __expf(2.0f * v));
}

__device__ __forceinline__ unsigned short f2bf(float f) {
    unsigned int u = __builtin_bit_cast(unsigned int, f);
    u += 0x7FFFu + ((u >> 16) & 1u);   // RNE
    return (unsigned short)(u >> 16);
}

__device__ __forceinline__ float bf2f(unsigned short s) {
    unsigned int u = ((unsigned int)s) << 16;
    return __builtin_bit_cast(float, u);
}

__device__ __forceinline__ unsigned int pkbf(float lo, float hi) {
#if __has_builtin(__builtin_amdgcn_cvt_pk_bf16_f32)
    bf16x2 v = __builtin_amdgcn_cvt_pk_bf16_f32(lo, hi);
    unsigned int r; __builtin_memcpy(&r, &v, 4); return r;
#else
    return (unsigned int)f2bf(lo) | ((unsigned int)f2bf(hi) << 16);
#endif
}

__device__ __forceinline__ f32x4 mfma16(u16x8 a, u16x8 b, f32x4 c) {
    return __builtin_amdgcn_mfma_f32_16x16x32_bf16(
        __builtin_bit_cast(bf16x8, a), __builtin_bit_cast(bf16x8, b), c, 0, 0, 0);
}

// ---------------- K1: zero cnt + gtotal (tiny; must precede hist) -----------
__global__ __launch_bounds__(256) void init_small_kernel(
    float4* __restrict__ p, int n4)
{
    int i = blockIdx.x * 256 + threadIdx.x;
    if (i < n4) p[i] = make_float4(0.f, 0.f, 0.f, 0.f);
}

// ---------------- K2: hist || weight conv || zero d_out || h -> bf16 --------
__global__ __launch_bounds__(256) void hist_conv_zero_hconv_kernel(
    const int* __restrict__ ei, int* __restrict__ cnt, int histBlocks,
    const float* __restrict__ We1, const float* __restrict__ We2,
    const float* __restrict__ Wx1, const float* __restrict__ Wn1,
    const float* __restrict__ Wn2,
    unsigned short* __restrict__ w1t, unsigned short* __restrict__ w2t,
    unsigned short* __restrict__ wx1t, unsigned short* __restrict__ wn1t,
    unsigned short* __restrict__ wn2t,
    float4* __restrict__ out4,
    const float* __restrict__ h, unsigned short* __restrict__ hb)
{
    int b = blockIdx.x, t = threadIdx.x;
    if (b < histBlocks) {
        atomicAdd(&cnt[ei[NE + b * 256 + t]], 1);
        return;
    }
    b -= histBlocks;
    if (b < CONVB) {
        int i = b * 256 + t;
        const int S1 = 128 * KP1;
        const int S2 = 128 * 128;
        const int S3 = 128 * 256;
        if (i < S1) {
            int n = i / KP1, k = i % KP1;
            w1t[i] = (k < 280) ? f2bf(We1[k * H + n]) : (unsigned short)0;
        } else if (i < S1 + S2) {
            int j = i - S1; int n = j / H, k = j % H;
            w2t[j] = f2bf(We2[k * H + n]);
        } else if (i < S1 + 2 * S2) {
            int j = i - S1 - S2; int n = j / H, k = j % H;
            wx1t[j] = f2bf(Wx1[k * H + n]);
        } else if (i < S1 + 2 * S2 + S3) {
            int j = i - S1 - 2 * S2; int n = j / 256, k = j % 256;
            wn1t[j] = f2bf(Wn1[k * H + n]);
        } else if (i < S1 + 3 * S2 + S3) {
            int j = i - S1 - 2 * S2 - S3; int n = j / H, k = j % H;
            wn2t[j] = f2bf(Wn2[k * H + n]);
        }
        return;
    }
    b -= CONVB;
    if (b < ZOB) {
        int i = b * 256 + t;
        if (i < N4OUT) out4[i] = make_float4(0.f, 0.f, 0.f, 0.f);
        return;
    }
    b -= ZOB;
    int j = b * 256 + t;                  // j < 800000, 8 floats each
    const float4* hp = (const float4*)h + (size_t)j * 2;
    float4 a = hp[0], c = hp[1];
    uint4 pk = { pkbf(a.x, a.y), pkbf(a.z, a.w), pkbf(c.x, c.y), pkbf(c.z, c.w) };
    ((uint4*)hb)[j] = pk;
}

// ---------------- K3: run-base allocation (no scan) -------------------------
// Group order is irrelevant for the segment sum; each dst just needs a
// contiguous slice. Wave-scan cnt, one global atomicAdd per wave.
__global__ __launch_bounds__(256) void alloc_kernel(
    const int* __restrict__ cnt, int* __restrict__ cur, int* __restrict__ gtot)
{
    int t = threadIdx.x;
    int d = blockIdx.x * 256 + t;
    int v = cnt[d];
    int incl = v;
    #pragma unroll
    for (int o = 1; o < 64; o <<= 1) {
        int u = __shfl_up(incl, o, 64);
        if ((t & 63) >= o) incl += u;
    }
    int total = __shfl(incl, 63, 64);
    int base = 0;
    if ((t & 63) == 63) base = atomicAdd(gtot, total);
    base = __shfl(base, 63, 64);
    cur[d] = base + incl - v;
}

// ---------------- K4: scatter sorted payload {src, dst, ea bf16x4} ----------
__global__ __launch_bounds__(256) void scatter_kernel(
    const int* __restrict__ ei, const float* __restrict__ edge_attr,
    int* __restrict__ cur, uint4* __restrict__ epay)
{
    int i = blockIdx.x * 256 + threadIdx.x;
    int s = ei[i], d = ei[NE + i];
    float4 ea = ((const float4*)edge_attr)[i];
    int p = atomicAdd(&cur[d], 1);
    uint4 pv = { (unsigned)s, (unsigned)d, pkbf(ea.x, ea.y), pkbf(ea.z, ea.w) };
    epay[p] = pv;
}

// ---------------- edge kernel (R3 body, NO swizzle) -------------------------
// 512 threads, 8 waves x 16feat x 64edges: each weight line touched by ONE
// wave per block. Partial reductions via epart/xpart arrays (plain stores +
// 8-way sum). LDS 44544B -> 3 blocks/CU (24 waves) -- measured faster than
// the 32-wave "diet" variants. min-waves 6 ((512,8) forced 32-VGPR spills).
// NO XCD swizzle: every swizzled variant ran 257-265 us; the identical body
// without it ran 242 (R3 vs R8 A/B: +10% stall, -2MB FETCH -- bad trade for
// a latency-bound kernel at 7% HBM).
__global__ __launch_bounds__(512, 6) void edge_kernel(
    const float* __restrict__ h, const float* __restrict__ x,
    const int* __restrict__ ei, const float* __restrict__ edge_attr,
    const unsigned short* __restrict__ w1t, const float* __restrict__ be1,
    const unsigned short* __restrict__ w2t, const float* __restrict__ be2,
    const float* __restrict__ Winf, const float* __restrict__ binf,
    const unsigned short* __restrict__ wx1t, const float* __restrict__ bx1,
    const float* __restrict__ Wx2,
    const uint4* __restrict__ epay, const unsigned short* __restrict__ hb,
    float* __restrict__ mi, float* __restrict__ dx)
{
    // zs dead after L1 K-loop: m1 aliases zs[0:EPB*BB], m2 the next EPB*BB
    // (2*EPB*BB = 17408 shorts <= EPB*ZB = 18944).
    __shared__ unsigned short zs[EPB * ZB];
    __shared__ float relx_s[EPB][3];
    __shared__ float eij_s[EPB];
    __shared__ float xg_s[EPB];
    __shared__ float epart[8][EPB];
    __shared__ float xpart[8][EPB];
    __shared__ int dst_s[EPB];
    __shared__ float winf_s[H];
    __shared__ float wx2_s[H];

    unsigned short* m1 = zs;
    unsigned short* m2 = zs + EPB * BB;

    const int t = threadIdx.x;
    const int e0 = blockIdx.x * EPB;
    const bool srt = (epay != nullptr);

    if (t >= 128 && t < 256) {
        winf_s[t - 128] = Winf[t - 128];
        wx2_s[t - 128] = Wx2[t - 128];
    }

    // Gather h[dst] -> z[0:128], h[src] -> z[128:256]; 8 lanes/edge, 64 edges.
    {
        int e = t >> 3, l = t & 7;
        unsigned short* zr = zs + e * ZB;
        if (srt) {
            uint4 pv = epay[e0 + e];
            const uint4* hd = (const uint4*)(hb + (size_t)pv.y * H);
            const uint4* hs = (const uint4*)(hb + (size_t)pv.x * H);
            uint4 a0 = hd[l * 2], a1 = hd[l * 2 + 1];
            *(uint4*)(zr + l * 16) = a0;
            *(uint4*)(zr + l * 16 + 8) = a1;
            uint4 c0 = hs[l * 2], c1 = hs[l * 2 + 1];
            *(uint4*)(zr + 128 + l * 16) = c0;
            *(uint4*)(zr + 128 + l * 16 + 8) = c1;
        } else {
            int s = ei[e0 + e], d = ei[NE + e0 + e];
            const float4* hd = (const float4*)(h + (size_t)d * H);
            const float4* hs = (const float4*)(h + (size_t)s * H);
            float4 v0 = hd[l * 4 + 0], v1 = hd[l * 4 + 1];
            float4 v2 = hd[l * 4 + 2], v3 = hd[l * 4 + 3];
            uint4 p0 = { pkbf(v0.x, v0.y), pkbf(v0.z, v0.w), pkbf(v1.x, v1.y), pkbf(v1.z, v1.w) };
            uint4 p1 = { pkbf(v2.x, v2.y), pkbf(v2.z, v2.w), pkbf(v3.x, v3.y), pkbf(v3.z, v3.w) };
            *(uint4*)(zr + l * 16) = p0;
            *(uint4*)(zr + l * 16 + 8) = p1;
            float4 w0 = hs[l * 4 + 0], w1 = hs[l * 4 + 1];
            float4 w2 = hs[l * 4 + 2], w3 = hs[l * 4 + 3];
            uint4 q0 = { pkbf(w0.x, w0.y), pkbf(w0.z, w0.w), pkbf(w1.x, w1.y), pkbf(w1.z, w1.w) };
            uint4 q1 = { pkbf(w2.x, w2.y), pkbf(w2.z, w2.w), pkbf(w3.x, w3.y), pkbf(w3.z, w3.w) };
            *(uint4*)(zr + 128 + l * 16) = q0;
            *(uint4*)(zr + 128 + l * 16 + 8) = q1;
        }
    }
    // Geometry + gaussians + edge_attr + pad; 1 thread/edge.
    if (t < EPB) {
        unsigned short* zr = zs + t * ZB;
        int s, d;
        if (srt) {
            uint4 pv = epay[e0 + t];
            s = (int)pv.x; d = (int)pv.y;
            *(unsigned int*)(zr + 276) = pv.z;   // ea[0..1] bf16
            *(unsigned int*)(zr + 278) = pv.w;   // ea[2..3] bf16
        } else {
            s = ei[e0 + t]; d = ei[NE + e0 + t];
            #pragma unroll
            for (int j = 0; j < 4; j++)
                zr[276 + j] = f2bf(edge_attr[(size_t)(e0 + t) * 4 + j]);
        }
        dst_s[t] = d;
        float rx = x[d * 3 + 0] - x[s * 3 + 0];
        float ry = x[d * 3 + 1] - x[s * 3 + 1];
        float rz = x[d * 3 + 2] - x[s * 3 + 2];
        float d2 = rx * rx + ry * ry + rz * rz;
        float dd = sqrtf(d2 + 1e-8f);
        float inv = frcp(dd + 1.0f);
        relx_s[t][0] = rx * inv;
        relx_s[t][1] = ry * inv;
        relx_s[t][2] = rz * inv;
        const float step = 10.0f / 19.0f;
        const float coeff = -0.5f / (step * step);
        #pragma unroll
        for (int g = 0; g < 20; g++) {
            float df = dd - step * (float)g;
            zr[256 + g] = f2bf(__expf(coeff * df * df));
        }
        #pragma unroll
        for (int j = 280; j < ZB; j++) zr[j] = 0;
    }
    __syncthreads();                                               // B

    const int wv = t >> 6, lane = t & 63;
    const int quad = lane >> 4, r16 = lane & 15;
    const int F = wv * 16;
    const int f0 = F + quad * 4;

    // Layer 1: (z @ We1)^T -> silu -> m1. 16 feat x 64 edges per wave.
    {
        f32x4 acc[4] = {};
        #pragma unroll
        for (int ks = 0; ks < KP1 / 32; ks++) {
            int ko = ks * 32 + quad * 8;
            u16x8 a = *(const u16x8*)(w1t + (size_t)(F + r16) * KP1 + ko);
            #pragma unroll
            for (int ci = 0; ci < 4; ci++) {
                u16x8 b = *(const u16x8*)(zs + (ci * 16 + r16) * ZB + ko);
                acc[ci] = mfma16(a, b, acc[ci]);
            }
        }
        __syncthreads();                                           // C
        float4 bv = *(const float4*)(be1 + f0);
        #pragma unroll
        for (int ci = 0; ci < 4; ci++) {
            int e = ci * 16 + r16;
            float s0 = silu_f(acc[ci][0] + bv.x);
            float s1 = silu_f(acc[ci][1] + bv.y);
            float s2 = silu_f(acc[ci][2] + bv.z);
            float s3 = silu_f(acc[ci][3] + bv.w);
            uint2 p = { pkbf(s0, s1), pkbf(s2, s3) };
            *(uint2*)(m1 + e * BB + f0) = p;
        }
    }
    __syncthreads();                                               // D

    // Layer 2: mij -> m2 (bf16). eij dot fused; partials to epart array.
    {
        f32x4 acc[4] = {};
        #pragma unroll
        for (int ks = 0; ks < H / 32; ks++) {
            int ko = ks * 32 + quad * 8;
            u16x8 a = *(const u16x8*)(w2t + (size_t)(F + r16) * H + ko);
            #pragma unroll
            for (int ci = 0; ci < 4; ci++) {
                u16x8 b = *(const u16x8*)(m1 + (ci * 16 + r16) * BB + ko);
                acc[ci] = mfma16(a, b, acc[ci]);
            }
        }
        float4 bv = *(const float4*)(be2 + f0);
        float4 wf = *(const float4*)(winf_s + f0);
        float ep[4];
        #pragma unroll
        for (int ci = 0; ci < 4; ci++) {
            int e = ci * 16 + r16;
            float s0 = silu_f(acc[ci][0] + bv.x);
            float s1 = silu_f(acc[ci][1] + bv.y);
            float s2 = silu_f(acc[ci][2] + bv.z);
            float s3 = silu_f(acc[ci][3] + bv.w);
            ep[ci] = s0 * wf.x + s1 * wf.y + s2 * wf.z + s3 * wf.w;
            uint2 p = { pkbf(s0, s1), pkbf(s2, s3) };
            *(uint2*)(m2 + e * BB + f0) = p;
        }
        #pragma unroll
        for (int ci = 0; ci < 4; ci++) {
            ep[ci] += __shfl_xor(ep[ci], 16, 64);
            ep[ci] += __shfl_xor(ep[ci], 32, 64);
        }
        if (quad == 0) {
            #pragma unroll
            for (int ci = 0; ci < 4; ci++)
                epart[wv][ci * 16 + r16] = ep[ci];
        }
    }
    __syncthreads();                                               // E

    // eij = sigmoid(sum + binf); 64 threads. (Ordered for segsum by F.)
    if (t < EPB) {
        float s = binf[0];
        #pragma unroll
        for (int w = 0; w < 8; w++) s += epart[w][t];
        eij_s[t] = sigmoid_f(s);
    }

    // Coord layer: silu(mij @ Wx1) . Wx2, never materialized.
    {
        f32x4 acc[4] = {};
        #pragma unroll
        for (int ks = 0; ks < H / 32; ks++) {
            int ko = ks * 32 + quad * 8;
            u16x8 a = *(const u16x8*)(wx1t + (size_t)(F + r16) * H + ko);
            #pragma unroll
            for (int ci = 0; ci < 4; ci++) {
                u16x8 b = *(const u16x8*)(m2 + (ci * 16 + r16) * BB + ko);
                acc[ci] = mfma16(a, b, acc[ci]);
            }
        }
        float4 bv = *(const float4*)(bx1 + f0);
        float4 wf = *(const float4*)(wx2_s + f0);
        float xp[4];
        #pragma unroll
        for (int ci = 0; ci < 4; ci++) {
            xp[ci] = silu_f(acc[ci][0] + bv.x) * wf.x
                   + silu_f(acc[ci][1] + bv.y) * wf.y
                   + silu_f(acc[ci][2] + bv.z) * wf.z
                   + silu_f(acc[ci][3] + bv.w) * wf.w;
        }
        #pragma unroll
        for (int ci = 0; ci < 4; ci++) {
            xp[ci] += __shfl_xor(xp[ci], 16, 64);
            xp[ci] += __shfl_xor(xp[ci], 32, 64);
        }
        if (quad == 0) {
            #pragma unroll
            for (int ci = 0; ci < 4; ci++)
                xpart[wv][ci * 16 + r16] = xp[ci];
        }
    }
    __syncthreads();                                               // F

    // xg = tanh(sum of partials); 64 threads, then barrier for the 3-thread
    // dx run-accumulation.
    if (t < EPB) {
        float xs = 0.f;
        #pragma unroll
        for (int w = 0; w < 8; w++) xs += xpart[w][t];
        xg_s[t] = tanh_f(xs);
    }
    __syncthreads();                                               // G

    // Segment sums over sorted runs: chunk-8 register prefetch breaks the
    // LDS-latency chain; one atomic per run; block-interior runs (dst wholly
    // owned, only in sorted mode) use a plain store.
    if (t < 128) {
        const int k = t;
        float acc = 0.f;
        int rs = 0;
        #pragma unroll
        for (int c = 0; c < EPB; c += 8) {
            float v[8];
            #pragma unroll
            for (int j = 0; j < 8; j++)
                v[j] = bf2f(m2[(c + j) * BB + k]) * eij_s[c + j];
            #pragma unroll
            for (int j = 0; j < 8; j++) {
                int e = c + j;
                acc += v[j];
                if (e == EPB - 1 || dst_s[e + 1] != dst_s[e]) {
                    float* p = &mi[(size_t)dst_s[e] * H + k];
                    if (srt && rs > 0 && e < EPB - 1) *p = acc;
                    else atomicAdd(p, acc);
                    acc = 0.f;
                    rs = e + 1;
                }
            }
        }
    } else if (t < 131) {
        const int dd = t - 128;
        float acc = 0.f;
        int rs = 0;
        #pragma unroll
        for (int c = 0; c < EPB; c += 8) {
            float v[8];
            #pragma unroll
            for (int j = 0; j < 8; j++)
                v[j] = relx_s[c + j][dd] * xg_s[c + j];
            #pragma unroll
            for (int j = 0; j < 8; j++) {
                int e = c + j;
                acc += v[j];
                if (e == EPB - 1 || dst_s[e + 1] != dst_s[e]) {
                    float* p = &dx[(size_t)dst_s[e] * 3 + dd];
                    if (srt && rs > 0 && e < EPB - 1) *p = acc;
                    else atomicAdd(p, acc);
                    acc = 0.f;
                    rs = e + 1;
                }
            }
        }
    }
}

// ---------------- node kernel (bf16 MFMA, 512 thr, 64 nodes) ----------------
// 8 waves x 16feat x 64nodes: weight rows loaded by ONE wave per block.
// LDS ~33.8KB -> 4 blocks/CU. min-waves 6 (8 caused register-squeeze spills).
__global__ __launch_bounds__(512, 6) void node_kernel(
    const float* __restrict__ h, const float* __restrict__ x,
    const float* __restrict__ mask,
    const unsigned short* __restrict__ wn1t, const float* __restrict__ bn1,
    const unsigned short* __restrict__ wn2t, const float* __restrict__ bn2,
    const unsigned short* __restrict__ hb,
    float* __restrict__ mi_hout, float* __restrict__ dx_xout)
{
    __shared__ unsigned short nzs[NPB * NZB];   // 16896 shorts; nbuf needs 8704

    unsigned short* nbuf = nzs;

    const int t = threadIdx.x;
    const int n0 = blockIdx.x * NPB;

    {
        int r = t >> 3, l = t & 7;
        int n = n0 + r;
        unsigned short* zr = nzs + r * NZB;
        if (n < NN) {
            const float4* mi4 = (const float4*)(mi_hout + (size_t)n * H);
            float4 v0 = mi4[l * 4 + 0], v1 = mi4[l * 4 + 1];
            float4 v2 = mi4[l * 4 + 2], v3 = mi4[l * 4 + 3];
            uint4 p0 = { pkbf(v0.x, v0.y), pkbf(v0.z, v0.w), pkbf(v1.x, v1.y), pkbf(v1.z, v1.w) };
            uint4 p1 = { pkbf(v2.x, v2.y), pkbf(v2.z, v2.w), pkbf(v3.x, v3.y), pkbf(v3.z, v3.w) };
            *(uint4*)(zr + l * 16) = p0;
            *(uint4*)(zr + l * 16 + 8) = p1;
            if (hb) {
                const uint4* hs = (const uint4*)(hb + (size_t)n * H);
                *(uint4*)(zr + 128 + l * 16) = hs[l * 2];
                *(uint4*)(zr + 128 + l * 16 + 8) = hs[l * 2 + 1];
            } else {
                const float4* h4 = (const float4*)(h + (size_t)n * H);
                float4 w0 = h4[l * 4 + 0], w1 = h4[l * 4 + 1];
                float4 w2 = h4[l * 4 + 2], w3 = h4[l * 4 + 3];
                uint4 q0 = { pkbf(w0.x, w0.y), pkbf(w0.z, w0.w), pkbf(w1.x, w1.y), pkbf(w1.z, w1.w) };
                uint4 q1 = { pkbf(w2.x, w2.y), pkbf(w2.z, w2.w), pkbf(w3.x, w3.y), pkbf(w3.z, w3.w) };
                *(uint4*)(zr + 128 + l * 16) = q0;
                *(uint4*)(zr + 128 + l * 16 + 8) = q1;
            }
        } else {
            uint4 zf = {0u, 0u, 0u, 0u};
            *(uint4*)(zr + l * 16) = zf;
            *(uint4*)(zr + l * 16 + 8) = zf;
            *(uint4*)(zr + 128 + l * 16) = zf;
            *(uint4*)(zr + 128 + l * 16 + 8) = zf;
        }
    }

    float xo = 0.f;
    int xn = -1, xdim = 0;
    if (t < NPB * 3) {
        int r = t / 3; xdim = t % 3;
        int n = n0 + r;
        if (n < NN) {
            xn = n;
            xo = x[(size_t)n * 3 + xdim] + dx_xout[(size_t)n * 3 + xdim] * mask[n];
        }
    }
    __syncthreads();

    if (xn >= 0) dx_xout[(size_t)xn * 3 + xdim] = xo;

    const int wv = t >> 6, lane = t & 63;
    const int quad = lane >> 4, r16 = lane & 15;
    const int F = wv * 16;
    const int f0 = F + quad * 4;

    // n1: silu(nz @ Wn1) -> nbuf (aliases nzs). 16 feat x 64 nodes per wave.
    {
        f32x4 acc[4] = {};
        #pragma unroll
        for (int ks = 0; ks < 2 * H / 32; ks++) {
            int ko = ks * 32 + quad * 8;
            u16x8 a = *(const u16x8*)(wn1t + (size_t)(F + r16) * (2 * H) + ko);
            #pragma unroll
            for (int ci = 0; ci < 4; ci++) {
                u16x8 b = *(const u16x8*)(nzs + (ci * 16 + r16) * NZB + ko);
                acc[ci] = mfma16(a, b, acc[ci]);
            }
        }
        __syncthreads();
        float4 bv = *(const float4*)(bn1 + f0);
        #pragma unroll
        for (int ci = 0; ci < 4; ci++) {
            int e = ci * 16 + r16;
            float s0 = silu_f(acc[ci][0] + bv.x);
            float s1 = silu_f(acc[ci][1] + bv.y);
            float s2 = silu_f(acc[ci][2] + bv.z);
            float s3 = silu_f(acc[ci][3] + bv.w);
            uint2 p = { pkbf(s0, s1), pkbf(s2, s3) };
            *(uint2*)(nbuf + e * BB + f0) = p;
        }
    }
    __syncthreads();

    // n2: (nbuf @ Wn2) + bn2 + h -> h_out
    {
        f32x4 acc[4] = {};
        #pragma unroll
        for (int ks = 0; ks < H / 32; ks++) {
            int ko = ks * 32 + quad * 8;
            u16x8 a = *(const u16x8*)(wn2t + (size_t)(F + r16) * H + ko);
            #pragma unroll
            for (int ci = 0; ci < 4; ci++) {
                u16x8 b = *(const u16x8*)(nbuf + (ci * 16 + r16) * BB + ko);
                acc[ci] = mfma16(a, b, acc[ci]);
            }
        }
        float4 bv = *(const float4*)(bn2 + f0);
        #pragma unroll
        for (int ci = 0; ci < 4; ci++) {
            int n = n0 + ci * 16 + r16;
            if (n < NN) {
                float4 hv = *(const float4*)(h + (size_t)n * H + f0);
                float4 o;
                o.x = hv.x + acc[ci][0] + bv.x;
                o.y = hv.y + acc[ci][1] + bv.y;
                o.z = hv.z + acc[ci][2] + bv.z;
                o.w = hv.w + acc[ci][3] + bv.w;
                *(float4*)(mi_hout + (size_t)n * H + f0) = o;
            }
        }
    }
}

extern "C" void kernel_launch(void* const* d_in, const int* in_sizes, int n_in,
                              void* d_out, int out_size, void* d_ws, size_t ws_size,
                              hipStream_t stream) {
    const float* h     = (const float*)d_in[0];
    const float* x     = (const float*)d_in[1];
    const int*   ei    = (const int*)d_in[2];
    const float* mask  = (const float*)d_in[3];
    const float* eattr = (const float*)d_in[4];
    const float* We1   = (const float*)d_in[5];
    const float* be1   = (const float*)d_in[6];
    const float* We2   = (const float*)d_in[7];
    const float* be2   = (const float*)d_in[8];
    const float* Winf  = (const float*)d_in[9];
    const float* binf  = (const float*)d_in[10];
    const float* Wx1   = (const float*)d_in[11];
    const float* bx1   = (const float*)d_in[12];
    const float* Wx2   = (const float*)d_in[13];
    const float* Wn1   = (const float*)d_in[14];
    const float* bn1   = (const float*)d_in[15];
    const float* Wn2   = (const float*)d_in[16];
    const float* bn2   = (const float*)d_in[17];

    float* mi = (float*)d_out;
    float* dx = mi + (size_t)NN * H;

    // ws layout (bytes):
    //   [0, 256K)            bf16 weights (237568 used)
    //   [256K, +200704)      cnt   (NBPAD ints)
    //   [.., +16)            gtotal
    //   [.., +200704)        cur   (NBPAD ints)
    //   [.., +12.8M)         hb    (bf16 h)
    //   [.., +10.24M)        epay  (uint4 per edge, dst-sorted)
    char* wsb  = (char*)d_ws;
    unsigned short* w1t  = (unsigned short*)wsb;
    unsigned short* w2t  = w1t + 128 * KP1;
    unsigned short* wx1t = w2t + 128 * H;
    unsigned short* wn1t = wx1t + 128 * H;
    unsigned short* wn2t = wn1t + 128 * 256;

    const size_t OFF_CNT  = 262144;
    const size_t OFF_GTOT = OFF_CNT + (size_t)NBPAD * 4;     // 462848
    const size_t OFF_CUR  = OFF_GTOT + 16;                   // 462864
    const size_t OFF_HB   = OFF_CUR + (size_t)NBPAD * 4;     // 663568
    const size_t OFF_EPAY = OFF_HB + (size_t)NN * H * 2;     // 13463568
    const size_t WS_NEED  = OFF_EPAY + (size_t)NE * 16;      // 23703568

    int*   cnt  = (int*)(wsb + OFF_CNT);
    int*   gtot = (int*)(wsb + OFF_GTOT);
    int*   cur  = (int*)(wsb + OFF_CUR);
    unsigned short* hb = (unsigned short*)(wsb + OFF_HB);
    uint4* epay = (uint4*)(wsb + OFF_EPAY);

    const bool full = (ws_size >= WS_NEED);

    // K1 (full only): zero cnt + gtotal (must precede hist). 12545 float4s.
    if (full) {
        const int n4c = (int)((OFF_CUR - OFF_CNT) / 16);
        init_small_kernel<<<(n4c + 255) / 256, 256, 0, stream>>>(
            (float4*)(wsb + OFF_CNT), n4c);
    }

    // K2: hist || weight conv || zero d_out || h->bf16 (co-run for overlap)
    {
        int hb_ = full ? HISTB : 0;
        int hc_ = full ? HCONVB : 0;
        hist_conv_zero_hconv_kernel<<<hb_ + CONVB + ZOB + hc_, 256, 0, stream>>>(
            ei, cnt, hb_, We1, We2, Wx1, Wn1, Wn2,
            w1t, w2t, wx1t, wn1t, wn2t, (float4*)d_out, h, hb);
    }

    if (full) {
        // K3: run-base alloc (tiny)
        alloc_kernel<<<ALLOCB, 256, 0, stream>>>(cnt, cur, gtot);
        // K4: sorted payload scatter
        scatter_kernel<<<NE / 256, 256, 0, stream>>>(ei, eattr, cur, epay);
    }

    edge_kernel<<<NE / EPB, 512, 0, stream>>>(
        h, x, ei, eattr, w1t, be1, w2t, be2, Winf, binf, wx1t, bx1, Wx2,
        full ? epay : (const uint4*)nullptr,
        full ? hb : (const unsigned short*)nullptr,
        mi, dx);

    node_kernel<<<(NN + NPB - 1) / NPB, 512, 0, stream>>>(
        h, x, mask, wn1t, bn1, wn2t, bn2,
        full ? hb : (const unsigned short*)nullptr,
        mi, dx);
}